// Round 2
// baseline (523.874 us; speedup 1.0000x reference)
//
#include <hip/hip_runtime.h>

// RoutedSelfAttention on MI355X.
// meanpool+cast -> router -> wcast (W^T bf16) -> MFMA GEMM qkv (3-buffer depth-2
// counted-vmcnt pipeline, XCD-swizzled, cheap-RoPE epilogue, v written transposed)
// -> bf16 MFMA flash attention (128-row Q tiles, dbuf K/vT, xor-swizzled LDS, XCD-swizzled,
//    setprio around MFMA) -> MFMA GEMM out.

typedef __attribute__((ext_vector_type(8))) short bf16x8;
typedef __attribute__((ext_vector_type(4))) float f32x4;

typedef const __attribute__((address_space(1))) unsigned short* gas_t;
typedef __attribute__((address_space(3))) unsigned short* las_t;

#define OFF_PART   (0ull)            // [32][16][1024] f32 partial mean sums (2 MB)
#define OFF_ROUTES (2ull << 20)      // [32] int
#define OFF_XB     (3ull << 20)      // x bf16 [32][512][1024] (32 MB); reused as ctx
#define OFF_WT     (40ull << 20)     // W^T bf16 [4][8][1024][1024] (64 MB)
#define OFF_QKV    (112ull << 20)    // q,k [p][32][16][512][64]; vT [32][16][64][512] (96 MB)

__device__ __forceinline__ unsigned short f2bf(float f){
  unsigned int u = __float_as_uint(f);
  u += 0x7fffu + ((u >> 16) & 1u);          // RNE
  return (unsigned short)(u >> 16);
}

// ---------------- router (meanpool fused with bf16 cast) ----------------

__global__ void meanpool_kernel(const float* __restrict__ x, float* __restrict__ part,
                                unsigned short* __restrict__ xb){
  const int b = blockIdx.x, lc = blockIdx.y, t = threadIdx.x;
  const size_t base = ((size_t)b*512 + lc*32)*1024;
  const float* xs = x + base;
  unsigned short* xo = xb + base;
  float a0=0.f, a1=0.f, a2=0.f, a3=0.f;
  for (int l = 0; l < 32; ++l){
    const float* row = xs + l*1024;
    unsigned short* orow = xo + l*1024;
    const float v0 = row[t], v1 = row[t+256], v2 = row[t+512], v3 = row[t+768];
    a0 += v0; a1 += v1; a2 += v2; a3 += v3;
    orow[t] = f2bf(v0); orow[t+256] = f2bf(v1); orow[t+512] = f2bf(v2); orow[t+768] = f2bf(v3);
  }
  float* o = part + ((size_t)b*16 + lc)*1024;
  o[t] = a0; o[t+256] = a1; o[t+512] = a2; o[t+768] = a3;
}

__global__ void router_kernel(const float* __restrict__ part,
                              const float* __restrict__ rw,
                              const float* __restrict__ rbias,
                              float* __restrict__ probs,
                              int* __restrict__ routes){
  const int b = blockIdx.x, t = threadIdx.x;
  __shared__ float xbar[1024];
  __shared__ float red[256*8];
  #pragma unroll
  for (int k = 0; k < 4; ++k){
    const int d = t + k*256;
    float s = 0.f;
    for (int lc = 0; lc < 16; ++lc) s += part[((size_t)b*16 + lc)*1024 + d];
    xbar[d] = s * (1.0f/512.0f);
  }
  __syncthreads();
  float p[8] = {0.f,0.f,0.f,0.f,0.f,0.f,0.f,0.f};
  #pragma unroll
  for (int k = 0; k < 4; ++k){
    const int d = t + k*256;
    const float xv = xbar[d];
    #pragma unroll
    for (int e = 0; e < 8; ++e) p[e] = fmaf(xv, rw[d*8 + e], p[e]);
  }
  #pragma unroll
  for (int e = 0; e < 8; ++e) red[t*8 + e] = p[e];
  __syncthreads();
  for (int s2 = 128; s2 > 0; s2 >>= 1){
    if (t < s2){
      #pragma unroll
      for (int e = 0; e < 8; ++e) red[t*8 + e] += red[(t + s2)*8 + e];
    }
    __syncthreads();
  }
  if (t == 0){
    float lg[8], mx = -3e38f; int am = 0;
    #pragma unroll
    for (int e = 0; e < 8; ++e){
      lg[e] = red[e] + rbias[e];
      if (lg[e] > mx){ mx = lg[e]; am = e; }
    }
    float sum = 0.f, ex[8];
    #pragma unroll
    for (int e = 0; e < 8; ++e){ ex[e] = __expf(lg[e] - mx); sum += ex[e]; }
    const float inv = 1.0f / sum;
    #pragma unroll
    for (int e = 0; e < 8; ++e) probs[b*8 + e] = ex[e] * inv;
    routes[b] = am;
  }
}

// ---------------- weight transpose-cast ----------------

__global__ void wcast_kernel(const float* __restrict__ W, unsigned short* __restrict__ Wt){
  __shared__ float tile[32][33];
  const int mtx = blockIdx.z;
  const float* Wm = W + (size_t)mtx*1024*1024;
  unsigned short* Wo = Wt + (size_t)mtx*1024*1024;
  const int t = threadIdx.x;
  const int c = t & 31, r0 = t >> 5;
  const int gx = blockIdx.x*32, gy = blockIdx.y*32;
  #pragma unroll
  for (int k = 0; k < 4; ++k){
    const int r = r0 + k*8;
    tile[r][c] = Wm[(size_t)(gy + r)*1024 + gx + c];
  }
  __syncthreads();
  #pragma unroll
  for (int k = 0; k < 4; ++k){
    const int r = r0 + k*8;
    Wo[(size_t)(gx + r)*1024 + gy + c] = f2bf(tile[c][r]);
  }
}

// ---------------- bf16 MFMA GEMM (128x128 tile, BK=32, xor-swizzled LDS) ----------------
// Depth-2 counted-vmcnt pipeline: 3 LDS buffers; per iter
//   s_waitcnt vmcnt(4) -> s_barrier -> STAGE(t+2) -> ds_read(t) -> 16 MFMA.
// Loads stay in flight across barriers (never drained to 0 in the main loop).
// XCD-contiguous slice swizzle.
// MODE 0: A=xb[b], W=Wt[p*8+route]; p<2: RoPE -> q/k [p][b][h][l][d]; p==2: vT [b][h][d][l]
// MODE 1: A=ctx[b], W=Wt_o[route]; -> d_out fp32

template<int MODE>
__global__ __launch_bounds__(256, 2) void gemm_kernel(
    const unsigned short* __restrict__ A,
    const unsigned short* __restrict__ Wt,
    const int* __restrict__ routes,
    unsigned short* __restrict__ qkvout,
    float* __restrict__ outf)
{
  __shared__ __align__(16) unsigned short As[3][128*32];
  __shared__ __align__(16) unsigned short Bs[3][128*32];

  // XCD-contiguous swizzle: physical XCD = dispatch_index % 8; relabel so each XCD owns
  // a contiguous run of slices (same-slice blocks share A/B panels in its L2).
  // z ordering: the 3 projections of one batch are adjacent (share the 1MB A panel).
  int wg = blockIdx.x + (blockIdx.y << 3) + (blockIdx.z << 5);
  wg = (wg & 7) * ((MODE == 0) ? 384 : 128) + (wg >> 3);
  const int z   = wg >> 5;
  const int rem = wg & 31;
  const int m0  = (rem >> 3) * 128;
  const int n0  = (rem & 7) * 128;
  const int b = (MODE == 0) ? (z / 3) : z;
  const int p = (MODE == 0) ? (z - b*3) : 0;

  const int route = routes[b];
  const unsigned short* Ab = A + (size_t)b*512*1024;
  const unsigned short* Wb = Wt + (size_t)((MODE == 0) ? (p*8 + route) : route)*1024*1024;
  const int t = threadIdx.x;
  const int lane = t & 63;
  const int wave = t >> 6;
  const int wm = (wave >> 1) * 64;
  const int wn = (wave & 1) * 64;
  const int quad = lane >> 4;
  const int ln = lane & 15;

  f32x4 acc[4][4] = {};

  // staging: unit u -> row u>>2, chunk (u&3); fetch global chunk (u&3)^((row>>1)&3)
  const int u0 = t, u1 = t + 256;
  const int r0s = u0 >> 2, c0s = (u0 & 3) ^ ((r0s >> 1) & 3);
  const int r1s = u1 >> 2, c1s = (u1 & 3) ^ ((r1s >> 1) & 3);
  const unsigned short* gA0 = Ab + (size_t)(m0 + r0s)*1024 + c0s*8;
  const unsigned short* gA1 = Ab + (size_t)(m0 + r1s)*1024 + c1s*8;
  const unsigned short* gB0 = Wb + (size_t)(n0 + r0s)*1024 + c0s*8;
  const unsigned short* gB1 = Wb + (size_t)(n0 + r1s)*1024 + c1s*8;
  las_t lA0 = (las_t)(&As[0][0] + u0*8), lA1 = (las_t)(&As[0][0] + u1*8);
  las_t lB0 = (las_t)(&Bs[0][0] + u0*8), lB1 = (las_t)(&Bs[0][0] + u1*8);

  // reader: row = w?+i*16+ln, chunk quad -> slot quad^((ln>>1)&3)  (wm/wn/i*16 vanish mod 4)
  const int swz = (quad ^ ((ln >> 1) & 3)) * 8;
  int offA[4], offB[4];
  #pragma unroll
  for (int i = 0; i < 4; ++i){
    offA[i] = (wm + i*16 + ln)*32 + swz;
    offB[i] = (wn + i*16 + ln)*32 + swz;
  }

#define STAGE(buf, kk) do { \
    const int bo_ = (buf)*4096; \
    __builtin_amdgcn_global_load_lds((gas_t)(gA0 + (kk)), lA0 + bo_, 16, 0, 0); \
    __builtin_amdgcn_global_load_lds((gas_t)(gA1 + (kk)), lA1 + bo_, 16, 0, 0); \
    __builtin_amdgcn_global_load_lds((gas_t)(gB0 + (kk)), lB0 + bo_, 16, 0, 0); \
    __builtin_amdgcn_global_load_lds((gas_t)(gB1 + (kk)), lB1 + bo_, 16, 0, 0); \
  } while (0)

#define COMPUTE(buf) do { \
    const unsigned short* Al_ = &As[buf][0]; \
    const unsigned short* Bl_ = &Bs[buf][0]; \
    bf16x8 av[4], bv[4]; \
    _Pragma("unroll") \
    for (int i = 0; i < 4; ++i){ \
      av[i] = *(const bf16x8*)(Al_ + offA[i]); \
      bv[i] = *(const bf16x8*)(Bl_ + offB[i]); \
    } \
    __builtin_amdgcn_s_setprio(1); \
    _Pragma("unroll") \
    for (int i = 0; i < 4; ++i) \
      _Pragma("unroll") \
      for (int j = 0; j < 4; ++j) \
        acc[i][j] = __builtin_amdgcn_mfma_f32_16x16x32_bf16(av[i], bv[j], acc[i][j], 0, 0, 0); \
    __builtin_amdgcn_s_setprio(0); \
  } while (0)

  STAGE(0, 0);
  STAGE(1, 32);
  // Main loop: tiles 0..29; each iter leaves the next tile's 4 loads in flight.
  for (int t8 = 0; t8 < 30; ++t8){
    asm volatile("s_waitcnt vmcnt(4)" ::: "memory");   // tile t landed; t+1 in flight
    __builtin_amdgcn_s_barrier();                      // publish all waves' stages
    __builtin_amdgcn_sched_barrier(0);                 // no motion across the barrier
    STAGE((t8 + 2) % 3, t8*32 + 64);
    COMPUTE(t8 % 3);
  }
  // Tail: tiles 30 (buf 0) and 31 (buf 1).
  asm volatile("s_waitcnt vmcnt(4)" ::: "memory");
  __builtin_amdgcn_s_barrier();
  __builtin_amdgcn_sched_barrier(0);
  COMPUTE(0);
  asm volatile("s_waitcnt vmcnt(0)" ::: "memory");
  __builtin_amdgcn_s_barrier();
  __builtin_amdgcn_sched_barrier(0);
  COMPUTE(1);
#undef STAGE
#undef COMPUTE

  if (MODE == 0){
    const size_t PSZ = (size_t)32*16*512*64;
    if (p < 2){
      // RoPE epilogue: 20 sincos instead of 64 — one base angle per (i,j), then
      // angle-addition rotation by invf across the 4 consecutive positions r.
      #pragma unroll
      for (int j = 0; j < 4; ++j){
        const int e  = n0 + wn + j*16 + ln;
        const int h  = e >> 6;
        const int eh = e & 63;
        const float invf = exp2f(-0.41524101f * (float)(eh >> 1)); // 10000^(-2i/64)
        float s1, c1; __sincosf(invf, &s1, &c1);
        unsigned short* outp = qkvout + ((((size_t)p*32 + b)*16 + h)*512)*64 + eh;
        const int l0 = m0 + wm + quad*4;
        #pragma unroll
        for (int i = 0; i < 4; ++i){
          float sn, cs;
          __sincosf((float)(l0 + i*16) * invf, &sn, &cs);
          #pragma unroll
          for (int r = 0; r < 4; ++r){
            const int l = l0 + i*16 + r;
            const float own = acc[i][j][r];
            const float par = __shfl_xor(own, 1, 64);
            const float v = (e & 1) ? fmaf(own, cs, par*sn) : fmaf(own, cs, -par*sn);
            outp[(size_t)l*64] = f2bf(v);
            const float nc = cs*c1 - sn*s1;     // rotate angle by +invf
            const float ns = sn*c1 + cs*s1;
            cs = nc; sn = ns;
          }
        }
      }
    } else {
      // vT[b][h][d][l]: pack 4 consecutive l (r=0..3) into one 8B store
      #pragma unroll
      for (int j = 0; j < 4; ++j){
        const int e  = n0 + wn + j*16 + ln;
        const int h  = e >> 6;
        const int eh = e & 63;
        unsigned short* outp = qkvout + 2*PSZ + (((size_t)b*16 + h)*64 + eh)*512;
        #pragma unroll
        for (int i = 0; i < 4; ++i){
          const int l0 = m0 + wm + i*16 + quad*4;
          ushort4 pk;
          pk.x = f2bf(acc[i][j][0]); pk.y = f2bf(acc[i][j][1]);
          pk.z = f2bf(acc[i][j][2]); pk.w = f2bf(acc[i][j][3]);
          *(ushort4*)(outp + l0) = pk;
        }
      }
    }
  } else {
    #pragma unroll
    for (int j = 0; j < 4; ++j){
      const int e = n0 + wn + j*16 + ln;
      #pragma unroll
      for (int i = 0; i < 4; ++i){
        #pragma unroll
        for (int r = 0; r < 4; ++r){
          const int l = m0 + wm + i*16 + quad*4 + r;
          outf[((size_t)b*512 + l)*1024 + e] = acc[i][j][r];
        }
      }
    }
  }
}

// ---------------- bf16 MFMA flash attention, 128-row Q blocks ----------------
// Block=(qt128,h,b), 4 waves; wave owns rows {qt*128+rg*64+w*16 .. +15} for rg=0,1.
// Q in registers; K and vT double-buffered via global_load_lds (xor-swizzled, 8 chunks/row);
// one barrier per 64-key tile. P round-trip through wave-local LDS (stride 72, 2-way free).
// XCD swizzle co-locates the 4 qt-blocks of each (b,h) -> K/V L2 reuse.

#define PSTR 72

__global__ __launch_bounds__(256, 3) void attn_kernel(
    const unsigned short* __restrict__ qkv,
    unsigned short* __restrict__ ctx)
{
  __shared__ __align__(16) unsigned short Ks[2][64*64];
  __shared__ __align__(16) unsigned short Vts[2][64*64];
  __shared__ __align__(16) unsigned short Ps[4][32*PSTR];

  // grid (4,16,32): wg = qt + 4h + 64b; co-locate same-(b,h) qt blocks per XCD.
  int wg = blockIdx.x + (blockIdx.y << 2) + (blockIdx.z << 6);
  wg = (wg & 7) * 256 + (wg >> 3);
  const int b  = wg >> 6;
  const int h  = (wg >> 2) & 15;
  const int qt = wg & 3;

  const size_t HO  = (((size_t)b)*16 + h)*512*64;
  const size_t PSZ = (size_t)32*16*512*64;
  const unsigned short* Qg  = qkv + HO;
  const unsigned short* Kg  = qkv + PSZ + HO;
  const unsigned short* Vtg = qkv + 2*PSZ + HO;   // [d][l], row stride 512

  const int t    = threadIdx.x;
  const int lane = t & 63;
  const int wave = t >> 6;
  const int quad = lane >> 4;
  const int ln   = lane & 15;

  // staging: unit u -> row u>>3, chunk u&7; fetch global chunk (u&7)^(row&7)
  const int u0 = t, u1 = t + 256;
  const int kr0 = u0 >> 3, kc0 = (u0 & 7) ^ (kr0 & 7);
  const int kr1 = u1 >> 3, kc1 = (u1 & 7) ^ (kr1 & 7);

  // Q fragments (A-layout) straight from global
  bf16x8 aq[2][2];
  #pragma unroll
  for (int rg = 0; rg < 2; ++rg){
    const int row = qt*128 + rg*64 + wave*16 + ln;
    #pragma unroll
    for (int ks = 0; ks < 2; ++ks)
      aq[rg][ks] = *(const bf16x8*)(Qg + (size_t)row*64 + ks*32 + quad*8);
  }

  const int ktEnd = 2*qt + 1;

  // prefetch kt=0
  __builtin_amdgcn_global_load_lds((gas_t)(Kg  + kr0*64  + kc0*8), (las_t)(Ks[0]  + u0*8), 16,0,0);
  __builtin_amdgcn_global_load_lds((gas_t)(Kg  + kr1*64  + kc1*8), (las_t)(Ks[0]  + u1*8), 16,0,0);
  __builtin_amdgcn_global_load_lds((gas_t)(Vtg + kr0*512 + kc0*8), (las_t)(Vts[0] + u0*8), 16,0,0);
  __builtin_amdgcn_global_load_lds((gas_t)(Vtg + kr1*512 + kc1*8), (las_t)(Vts[0] + u1*8), 16,0,0);

  float m_r[2][4], l_r[2][4];
  #pragma unroll
  for (int rg = 0; rg < 2; ++rg)
    #pragma unroll
    for (int r = 0; r < 4; ++r){ m_r[rg][r] = -3e38f; l_r[rg][r] = 0.f; }
  f32x4 o[2][4] = {};

  const int swzl = ln & 7;            // reader xor (row&7 == ln&7 for rows kn*16+ln / dn*16+ln)
  unsigned short* Pw = Ps[wave];
  const int rowoff = wave*16 + quad*4;

  for (int kt = 0; kt <= ktEnd; ++kt){
    __syncthreads();                  // drains kt's loads; protects other buffer's readers
    if (kt < ktEnd){
      const unsigned short* Kn  = Kg + (kt+1)*4096;
      const int col = (kt+1)*64;
      unsigned short* kb = Ks[(kt+1)&1];
      unsigned short* vb = Vts[(kt+1)&1];
      __builtin_amdgcn_global_load_lds((gas_t)(Kn  + kr0*64 + kc0*8),        (las_t)(kb + u0*8), 16,0,0);
      __builtin_amdgcn_global_load_lds((gas_t)(Kn  + kr1*64 + kc1*8),        (las_t)(kb + u1*8), 16,0,0);
      __builtin_amdgcn_global_load_lds((gas_t)(Vtg + kr0*512 + col + kc0*8), (las_t)(vb + u0*8), 16,0,0);
      __builtin_amdgcn_global_load_lds((gas_t)(Vtg + kr1*512 + col + kc1*8), (las_t)(vb + u1*8), 16,0,0);
    }
    const unsigned short* ks_ = Ks[kt&1];
    const unsigned short* vt_ = Vts[kt&1];

    #pragma unroll
    for (int rg = 0; rg < 2; ++rg){
      if (rg == 0 && kt > 2*qt) continue;       // rg0 fully masked only at kt==ktEnd
      const bool diag = (kt == 2*qt + rg);

      f32x4 s[4] = {};
      __builtin_amdgcn_s_setprio(1);
      #pragma unroll
      for (int ks2 = 0; ks2 < 2; ++ks2){
        #pragma unroll
        for (int kn = 0; kn < 4; ++kn){
          const bf16x8 bk = *(const bf16x8*)(ks_ + (kn*16+ln)*64 + (((quad + ks2*4) ^ swzl))*8);
          s[kn] = __builtin_amdgcn_mfma_f32_16x16x32_bf16(aq[rg][ks2], bk, s[kn], 0, 0, 0);
        }
      }
      __builtin_amdgcn_s_setprio(0);

      float p[4][4], lm[4] = {-3e38f,-3e38f,-3e38f,-3e38f};
      #pragma unroll
      for (int kn = 0; kn < 4; ++kn){
        const int col = kn*16 + ln;
        #pragma unroll
        for (int r = 0; r < 4; ++r){
          float v = s[kn][r] * 0.125f;
          if (diag && col > rowoff + r) v = -1e9f;
          p[kn][r] = v;
          lm[r] = fmaxf(lm[r], v);
        }
      }
      #pragma unroll
      for (int off = 1; off < 16; off <<= 1)
        #pragma unroll
        for (int r = 0; r < 4; ++r)
          lm[r] = fmaxf(lm[r], __shfl_xor(lm[r], off, 64));
      float alpha[4], rsum[4];
      #pragma unroll
      for (int r = 0; r < 4; ++r){
        const float mn = fmaxf(m_r[rg][r], lm[r]);
        alpha[r] = __expf(m_r[rg][r] - mn);
        m_r[rg][r] = mn;
      }
      #pragma unroll
      for (int kn = 0; kn < 4; ++kn)
        #pragma unroll
        for (int r = 0; r < 4; ++r)
          p[kn][r] = __expf(p[kn][r] - m_r[rg][r]);
      #pragma unroll
      for (int r = 0; r < 4; ++r)
        rsum[r] = (p[0][r] + p[1][r]) + (p[2][r] + p[3][r]);
      #pragma unroll
      for (int off = 1; off < 16; off <<= 1)
        #pragma unroll
        for (int r = 0; r < 4; ++r)
          rsum[r] += __shfl_xor(rsum[r], off, 64);
      #pragma unroll
      for (int r = 0; r < 4; ++r) l_r[rg][r] = l_r[rg][r]*alpha[r] + rsum[r];
      #pragma unroll
      for (int dn = 0; dn < 4; ++dn)
        #pragma unroll
        for (int r = 0; r < 4; ++r)
          o[rg][dn][r] *= alpha[r];

      // P: C-layout -> wave-local LDS [row-in-rg 0..31][key], A-layout source
      #pragma unroll
      for (int kn = 0; kn < 4; ++kn)
        #pragma unroll
        for (int r = 0; r < 4; ++r)
          Pw[(rg*16 + quad*4 + r)*PSTR + kn*16 + ln] = f2bf(p[kn][r]);

      __builtin_amdgcn_s_setprio(1);
      #pragma unroll
      for (int ks2 = 0; ks2 < 2; ++ks2){
        const bf16x8 ap = *(const bf16x8*)(Pw + (rg*16 + ln)*PSTR + quad*8 + ks2*32);
        #pragma unroll
        for (int dn = 0; dn < 4; ++dn){
          const bf16x8 bv = *(const bf16x8*)(vt_ + (dn*16+ln)*64 + (((quad + ks2*4) ^ swzl))*8);
          o[rg][dn] = __builtin_amdgcn_mfma_f32_16x16x32_bf16(ap, bv, o[rg][dn], 0, 0, 0);
        }
      }
      __builtin_amdgcn_s_setprio(0);
    }
  }

  #pragma unroll
  for (int rg = 0; rg < 2; ++rg){
    #pragma unroll
    for (int r = 0; r < 4; ++r){
      const float inv = 1.0f / l_r[rg][r];
      const int row = qt*128 + rg*64 + wave*16 + quad*4 + r;
      unsigned short* op = ctx + ((size_t)b*512 + row)*1024 + h*64 + ln;
      #pragma unroll
      for (int dn = 0; dn < 4; ++dn)
        op[dn*16] = f2bf(o[rg][dn][r] * inv);
    }
  }
}

// ---------------- launch ----------------

extern "C" void kernel_launch(void* const* d_in, const int* in_sizes, int n_in,
                              void* d_out, int out_size, void* d_ws, size_t ws_size,
                              hipStream_t stream) {
  const float* x     = (const float*)d_in[0];
  const float* qw    = (const float*)d_in[1];
  const float* kw    = (const float*)d_in[2];
  const float* vw    = (const float*)d_in[3];
  const float* ow    = (const float*)d_in[4];
  const float* rw    = (const float*)d_in[5];
  const float* rbias = (const float*)d_in[6];
  float* out = (float*)d_out;
  char* ws = (char*)d_ws;

  float* part            = (float*)(ws + OFF_PART);
  int* routes            = (int*)(ws + OFF_ROUTES);
  unsigned short* xb     = (unsigned short*)(ws + OFF_XB);
  unsigned short* wt     = (unsigned short*)(ws + OFF_WT);
  unsigned short* qkvbuf = (unsigned short*)(ws + OFF_QKV);
  unsigned short* ctx    = xb;
  float* probs = out + (size_t)32*512*1024;

  meanpool_kernel<<<dim3(32, 16), 256, 0, stream>>>(x, part, xb);
  router_kernel<<<32, 256, 0, stream>>>(part, rw, rbias, probs, routes);
  wcast_kernel<<<dim3(32, 32, 8), 256, 0, stream>>>(qw, wt);
  wcast_kernel<<<dim3(32, 32, 8), 256, 0, stream>>>(kw, wt + (size_t)8*1024*1024);
  wcast_kernel<<<dim3(32, 32, 8), 256, 0, stream>>>(vw, wt + (size_t)16*1024*1024);
  wcast_kernel<<<dim3(32, 32, 8), 256, 0, stream>>>(ow, wt + (size_t)24*1024*1024);
  gemm_kernel<0><<<dim3(8, 4, 96), 256, 0, stream>>>(xb, wt, routes, qkvbuf, nullptr);
  attn_kernel<<<dim3(4, 16, 32), 256, 0, stream>>>(qkvbuf, ctx);
  gemm_kernel<1><<<dim3(8, 4, 32), 256, 0, stream>>>(ctx, wt + (size_t)24*1024*1024, routes,
                                                     nullptr, out);
}

// Round 3
// 516.186 us; speedup vs baseline: 1.0149x; 1.0149x over previous
//
#include <hip/hip_runtime.h>

// RoutedSelfAttention on MI355X.
// meanpool+cast -> router -> wcast (W^T bf16) -> MFMA GEMM qkv (256x256 tile, BK=64,
// 8 waves, 4-phase/K-tile pipelined schedule: counted lgkm/vmcnt, reg-frag prefetch,
// setprio, XCD-swizzled, cheap-RoPE epilogue, v written transposed)
// -> bf16 MFMA flash attention -> MFMA GEMM out (same template).

typedef __attribute__((ext_vector_type(8))) short bf16x8;
typedef __attribute__((ext_vector_type(4))) float f32x4;

typedef const __attribute__((address_space(1))) unsigned short* gas_t;
typedef __attribute__((address_space(3))) unsigned short* las_t;

#define OFF_PART   (0ull)            // [32][16][1024] f32 partial mean sums (2 MB)
#define OFF_ROUTES (2ull << 20)      // [32] int
#define OFF_XB     (3ull << 20)      // x bf16 [32][512][1024] (32 MB); reused as ctx
#define OFF_WT     (40ull << 20)     // W^T bf16 [4][8][1024][1024] (64 MB)
#define OFF_QKV    (112ull << 20)    // q,k [p][32][16][512][64]; vT [32][16][64][512] (96 MB)

__device__ __forceinline__ unsigned short f2bf(float f){
  unsigned int u = __float_as_uint(f);
  u += 0x7fffu + ((u >> 16) & 1u);          // RNE
  return (unsigned short)(u >> 16);
}

// ---------------- router (meanpool fused with bf16 cast) ----------------

__global__ void meanpool_kernel(const float* __restrict__ x, float* __restrict__ part,
                                unsigned short* __restrict__ xb){
  const int b = blockIdx.x, lc = blockIdx.y, t = threadIdx.x;
  const size_t base = ((size_t)b*512 + lc*32)*1024;
  const float* xs = x + base;
  unsigned short* xo = xb + base;
  float a0=0.f, a1=0.f, a2=0.f, a3=0.f;
  for (int l = 0; l < 32; ++l){
    const float* row = xs + l*1024;
    unsigned short* orow = xo + l*1024;
    const float v0 = row[t], v1 = row[t+256], v2 = row[t+512], v3 = row[t+768];
    a0 += v0; a1 += v1; a2 += v2; a3 += v3;
    orow[t] = f2bf(v0); orow[t+256] = f2bf(v1); orow[t+512] = f2bf(v2); orow[t+768] = f2bf(v3);
  }
  float* o = part + ((size_t)b*16 + lc)*1024;
  o[t] = a0; o[t+256] = a1; o[t+512] = a2; o[t+768] = a3;
}

__global__ void router_kernel(const float* __restrict__ part,
                              const float* __restrict__ rw,
                              const float* __restrict__ rbias,
                              float* __restrict__ probs,
                              int* __restrict__ routes){
  const int b = blockIdx.x, t = threadIdx.x;
  __shared__ float xbar[1024];
  __shared__ float red[256*8];
  #pragma unroll
  for (int k = 0; k < 4; ++k){
    const int d = t + k*256;
    float s = 0.f;
    for (int lc = 0; lc < 16; ++lc) s += part[((size_t)b*16 + lc)*1024 + d];
    xbar[d] = s * (1.0f/512.0f);
  }
  __syncthreads();
  float p[8] = {0.f,0.f,0.f,0.f,0.f,0.f,0.f,0.f};
  #pragma unroll
  for (int k = 0; k < 4; ++k){
    const int d = t + k*256;
    const float xv = xbar[d];
    #pragma unroll
    for (int e = 0; e < 8; ++e) p[e] = fmaf(xv, rw[d*8 + e], p[e]);
  }
  #pragma unroll
  for (int e = 0; e < 8; ++e) red[t*8 + e] = p[e];
  __syncthreads();
  for (int s2 = 128; s2 > 0; s2 >>= 1){
    if (t < s2){
      #pragma unroll
      for (int e = 0; e < 8; ++e) red[t*8 + e] += red[(t + s2)*8 + e];
    }
    __syncthreads();
  }
  if (t == 0){
    float lg[8], mx = -3e38f; int am = 0;
    #pragma unroll
    for (int e = 0; e < 8; ++e){
      lg[e] = red[e] + rbias[e];
      if (lg[e] > mx){ mx = lg[e]; am = e; }
    }
    float sum = 0.f, ex[8];
    #pragma unroll
    for (int e = 0; e < 8; ++e){ ex[e] = __expf(lg[e] - mx); sum += ex[e]; }
    const float inv = 1.0f / sum;
    #pragma unroll
    for (int e = 0; e < 8; ++e) probs[b*8 + e] = ex[e] * inv;
    routes[b] = am;
  }
}

// ---------------- weight transpose-cast ----------------

__global__ void wcast_kernel(const float* __restrict__ W, unsigned short* __restrict__ Wt){
  __shared__ float tile[32][33];
  const int mtx = blockIdx.z;
  const float* Wm = W + (size_t)mtx*1024*1024;
  unsigned short* Wo = Wt + (size_t)mtx*1024*1024;
  const int t = threadIdx.x;
  const int c = t & 31, r0 = t >> 5;
  const int gx = blockIdx.x*32, gy = blockIdx.y*32;
  #pragma unroll
  for (int k = 0; k < 4; ++k){
    const int r = r0 + k*8;
    tile[r][c] = Wm[(size_t)(gy + r)*1024 + gx + c];
  }
  __syncthreads();
  #pragma unroll
  for (int k = 0; k < 4; ++k){
    const int r = r0 + k*8;
    Wo[(size_t)(gx + r)*1024 + gy + c] = f2bf(tile[c][r]);
  }
}

// ---------------- bf16 MFMA GEMM, 256x256 tile, BK=64, 8 waves, phase pipeline --------
// Tile T (of 16) lives in LDS buf T&1. Group g (one K-tile): 4 phases, each:
//   { ds_read frags for NEXT quadrant | barrier | counted lgkmcnt | setprio+16 MFMA | barrier }.
// All 8 staging loads for tile g+2 issue at phase 3 (buf g&1, reads drained at phase 2 by
// lgkmcnt(0) before its closing barrier); vmcnt(8) once per K-tile keeps 8 loads in flight.
// LDS xor swizzle: slot = chunk ^ (row&7); reader slot = chunk ^ (ln&7). 0 bank conflicts.
// MODE 0: A=xb[b], W=Wt[p*8+route]; p<2: RoPE -> q/k [p][b][h][l][d]; p==2: vT [b][h][d][l]
// MODE 1: A=ctx[b], W=Wt_o[route]; -> d_out fp32

template<int MODE>
__global__ __launch_bounds__(512, 2) void gemm_kernel(
    const unsigned short* __restrict__ A,
    const unsigned short* __restrict__ Wt,
    const int* __restrict__ routes,
    unsigned short* __restrict__ qkvout,
    float* __restrict__ outf)
{
  __shared__ __align__(16) unsigned short As[2][256*64];
  __shared__ __align__(16) unsigned short Bs[2][256*64];

  // XCD-contiguous swizzle (nwg % 8 == 0): XCD k owns a contiguous run of wg;
  // decode from wg so each XCD gets contiguous slices (A-panel + W reuse in its L2).
  const int f = blockIdx.x + blockIdx.y*8;
  const int CH = (MODE == 0) ? 96 : 32;      // nwg/8
  const int wg = (f & 7)*CH + (f >> 3);
  const int slice = wg >> 3;
  const int tile  = wg & 7;
  const int m0 = (tile >> 2)*256;
  const int n0 = (tile & 3)*256;
  const int b = (MODE == 0) ? (slice/3) : slice;   // slice = b*3+p keeps A-panel adjacent
  const int p = (MODE == 0) ? (slice - b*3) : 0;

  const int route = routes[b];
  const unsigned short* Ab = A + (size_t)b*512*1024;
  const unsigned short* Wb = Wt + (size_t)((MODE == 0) ? (p*8 + route) : route)*1024*1024;

  const int t = threadIdx.x;
  const int lane = t & 63;
  const int wave = t >> 6;          // 0..7
  const int wm = (wave >> 2)*128;   // 2 waves in M
  const int wn = (wave & 3)*64;     // 4 waves in N
  const int quad = lane >> 4;
  const int ln = lane & 15;

  // ---- staging addressing: unit u = t + k*512; row u>>3 (0..255), lds slot u&7,
  //      global chunk (u&7)^((u>>3)&7). (u>>3)&7 invariant in k (64 rows/k step).
  const int srow = t >> 3;
  const int sch  = (t & 7) ^ (srow & 7);
  const unsigned short* gA0 = Ab + (size_t)(m0 + srow)*1024 + sch*8;
  const unsigned short* gB0 = Wb + (size_t)(n0 + srow)*1024 + sch*8;

  // ---- reader offsets (elems): frag(row0+f*16, ks): row = w? + f*16 + ln,
  //      slot = (ks*4+quad) ^ (ln&7); row stride 64 elems.
  const int w8 = ln & 7;
  const int aO0 = (wm + ln)*64 + ((quad    ) ^ w8)*8;
  const int aO1 = (wm + ln)*64 + ((quad + 4) ^ w8)*8;
  const int bO0 = (wn + ln)*64 + ((quad    ) ^ w8)*8;
  const int bO1 = (wn + ln)*64 + ((quad + 4) ^ w8)*8;

  f32x4 acc[8][4] = {};
  bf16x8 a0[4][2], a1[4][2], b01[2][2], b23[2][2];

#define STAGE(c_, T_) do { \
    const size_t ko_ = (size_t)(T_)*64; \
    las_t dA_ = (las_t)(&As[c_][0]) + (size_t)t*8; \
    las_t dB_ = (las_t)(&Bs[c_][0]) + (size_t)t*8; \
    _Pragma("unroll") \
    for (int k_ = 0; k_ < 4; ++k_){ \
      __builtin_amdgcn_global_load_lds((gas_t)(gA0 + ko_ + (size_t)k_*65536), dA_ + k_*4096, 16, 0, 0); \
      __builtin_amdgcn_global_load_lds((gas_t)(gB0 + ko_ + (size_t)k_*65536), dB_ + k_*4096, 16, 0, 0); \
    } \
  } while (0)

#define RD(ptr_, off_) (*(const bf16x8*)((ptr_) + (off_)))
#define READ_F0(pA_, pB_) do { \
    _Pragma("unroll") for (int f_ = 0; f_ < 4; ++f_){ \
      a0[f_][0] = RD(pA_, aO0 + f_*1024); a0[f_][1] = RD(pA_, aO1 + f_*1024); } \
    _Pragma("unroll") for (int f_ = 0; f_ < 2; ++f_){ \
      b01[f_][0] = RD(pB_, bO0 + f_*1024); b01[f_][1] = RD(pB_, bO1 + f_*1024); } \
  } while (0)
#define READ_F1(pA_) do { \
    _Pragma("unroll") for (int f_ = 0; f_ < 4; ++f_){ \
      a1[f_][0] = RD(pA_, aO0 + (4+f_)*1024); a1[f_][1] = RD(pA_, aO1 + (4+f_)*1024); } \
  } while (0)
#define READ_F2(pB_) do { \
    _Pragma("unroll") for (int f_ = 0; f_ < 2; ++f_){ \
      b23[f_][0] = RD(pB_, bO0 + (2+f_)*1024); b23[f_][1] = RD(pB_, bO1 + (2+f_)*1024); } \
  } while (0)

#define MSET(AF_, BF_, IB_, JB_) do { \
    _Pragma("unroll") for (int f_ = 0; f_ < 4; ++f_) \
    _Pragma("unroll") for (int n_ = 0; n_ < 2; ++n_) \
    _Pragma("unroll") for (int k_ = 0; k_ < 2; ++k_) \
      acc[IB_+f_][JB_+n_] = __builtin_amdgcn_mfma_f32_16x16x32_bf16( \
          AF_[f_][k_], BF_[n_][k_], acc[IB_+f_][JB_+n_], 0, 0, 0); \
  } while (0)

  // prologue: stage tiles 0,1; ensure tile 0 landed for everyone; prefetch its F0 frags
  STAGE(0, 0);
  STAGE(1, 1);
  asm volatile("s_waitcnt vmcnt(8)" ::: "memory");
  __builtin_amdgcn_s_barrier();
  READ_F0((&As[0][0]), (&Bs[0][0]));

  for (int g = 0; g < 16; ++g){
    const int c = g & 1;
    const unsigned short* pA  = &As[c][0];
    const unsigned short* pB  = &Bs[c][0];
    const unsigned short* pAn = &As[c ^ 1][0];
    const unsigned short* pBn = &Bs[c ^ 1][0];

    // phase 0: prefetch a1; compute S0 = a0 x b01 (waits F0, leaves F1 in flight)
    READ_F1(pA);
    __builtin_amdgcn_s_barrier();
    asm volatile("s_waitcnt lgkmcnt(8)" ::: "memory");
    __builtin_amdgcn_sched_barrier(0);
    __builtin_amdgcn_s_setprio(1);
    MSET(a0, b01, 0, 0);
    __builtin_amdgcn_s_setprio(0);
    __builtin_amdgcn_s_barrier();

    // phase 1: prefetch b23; compute S1 = a1 x b01 (waits F1, leaves F2 in flight)
    READ_F2(pB);
    __builtin_amdgcn_s_barrier();
    asm volatile("s_waitcnt lgkmcnt(4)" ::: "memory");
    __builtin_amdgcn_sched_barrier(0);
    __builtin_amdgcn_s_setprio(1);
    MSET(a1, b01, 4, 0);
    __builtin_amdgcn_s_setprio(0);
    __builtin_amdgcn_s_barrier();

    // phase 2: compute S2 = a1 x b23; drain ALL ds_reads before closing barrier so
    // phase 3's stage into buf c cannot overwrite rows with reads still pending.
    asm volatile("s_waitcnt lgkmcnt(0)" ::: "memory");
    __builtin_amdgcn_sched_barrier(0);
    __builtin_amdgcn_s_setprio(1);
    MSET(a1, b23, 4, 2);
    __builtin_amdgcn_s_setprio(0);
    __builtin_amdgcn_s_barrier();

    // phase 3: stage tile g+2 -> buf c; vmcnt once per K-tile (tile g+1 landed,
    // tile g+2's 8 loads stay in flight); compute S3 = a0 x b23; then prefetch
    // next tile's F0 from buf c^1 (WAR on a0/b01 keeps it after S3).
    if (g < 14){
      STAGE(c, g + 2);
      asm volatile("s_waitcnt vmcnt(8)" ::: "memory");
    } else if (g == 14){
      asm volatile("s_waitcnt vmcnt(0)" ::: "memory");
    }
    __builtin_amdgcn_s_barrier();
    __builtin_amdgcn_s_setprio(1);
    MSET(a0, b23, 0, 2);
    __builtin_amdgcn_s_setprio(0);
    if (g < 15) READ_F0(pAn, pBn);
    __builtin_amdgcn_s_barrier();
  }
#undef STAGE
#undef RD
#undef READ_F0
#undef READ_F1
#undef READ_F2
#undef MSET

  if (MODE == 0){
    const size_t PSZ = (size_t)32*16*512*64;
    if (p < 2){
      // RoPE epilogue: base angle per (fn,fm), then angle-addition rotation by invf
      // across the 4 consecutive positions r.
      #pragma unroll
      for (int fn = 0; fn < 4; ++fn){
        const int e  = n0 + wn + fn*16 + ln;
        const int h  = e >> 6;
        const int eh = e & 63;
        const float invf = exp2f(-0.41524101f * (float)(eh >> 1)); // 10000^(-2i/64)
        float s1, c1; __sincosf(invf, &s1, &c1);
        unsigned short* outp = qkvout + ((((size_t)p*32 + b)*16 + h)*512)*64 + eh;
        #pragma unroll
        for (int fm = 0; fm < 8; ++fm){
          const int l0 = m0 + wm + fm*16 + quad*4;
          float sn, cs;
          __sincosf((float)l0 * invf, &sn, &cs);
          #pragma unroll
          for (int r = 0; r < 4; ++r){
            const int l = l0 + r;
            const float own = acc[fm][fn][r];
            const float par = __shfl_xor(own, 1, 64);
            const float v = (e & 1) ? fmaf(own, cs, par*sn) : fmaf(own, cs, -par*sn);
            outp[(size_t)l*64] = f2bf(v);
            const float nc = cs*c1 - sn*s1;     // rotate angle by +invf
            const float ns = sn*c1 + cs*s1;
            cs = nc; sn = ns;
          }
        }
      }
    } else {
      // vT[b][h][d][l]: pack 4 consecutive l (r=0..3) into one 8B store
      #pragma unroll
      for (int fn = 0; fn < 4; ++fn){
        const int e  = n0 + wn + fn*16 + ln;
        const int h  = e >> 6;
        const int eh = e & 63;
        unsigned short* outp = qkvout + 2*PSZ + (((size_t)b*16 + h)*64 + eh)*512;
        #pragma unroll
        for (int fm = 0; fm < 8; ++fm){
          const int l0 = m0 + wm + fm*16 + quad*4;
          ushort4 pk;
          pk.x = f2bf(acc[fm][fn][0]); pk.y = f2bf(acc[fm][fn][1]);
          pk.z = f2bf(acc[fm][fn][2]); pk.w = f2bf(acc[fm][fn][3]);
          *(ushort4*)(outp + l0) = pk;
        }
      }
    }
  } else {
    #pragma unroll
    for (int fn = 0; fn < 4; ++fn){
      const int e = n0 + wn + fn*16 + ln;
      #pragma unroll
      for (int fm = 0; fm < 8; ++fm){
        #pragma unroll
        for (int r = 0; r < 4; ++r){
          const int l = m0 + wm + fm*16 + quad*4 + r;
          outf[((size_t)b*512 + l)*1024 + e] = acc[fm][fn][r];
        }
      }
    }
  }
}

// ---------------- bf16 MFMA flash attention, 128-row Q blocks ----------------
// Block=(qt128,h,b), 4 waves; wave owns rows {qt*128+rg*64+w*16 .. +15} for rg=0,1.
// Q in registers; K and vT double-buffered via global_load_lds (xor-swizzled, 8 chunks/row);
// one barrier per 64-key tile. P round-trip through wave-local LDS (stride 72, 2-way free).
// XCD swizzle co-locates the 4 qt-blocks of each (b,h) -> K/V L2 reuse.

#define PSTR 72

__global__ __launch_bounds__(256, 3) void attn_kernel(
    const unsigned short* __restrict__ qkv,
    unsigned short* __restrict__ ctx)
{
  __shared__ __align__(16) unsigned short Ks[2][64*64];
  __shared__ __align__(16) unsigned short Vts[2][64*64];
  __shared__ __align__(16) unsigned short Ps[4][32*PSTR];

  // grid (4,16,32): wg = qt + 4h + 64b; co-locate same-(b,h) qt blocks per XCD.
  int wg = blockIdx.x + (blockIdx.y << 2) + (blockIdx.z << 6);
  wg = (wg & 7) * 256 + (wg >> 3);
  const int b  = wg >> 6;
  const int h  = (wg >> 2) & 15;
  const int qt = wg & 3;

  const size_t HO  = (((size_t)b)*16 + h)*512*64;
  const size_t PSZ = (size_t)32*16*512*64;
  const unsigned short* Qg  = qkv + HO;
  const unsigned short* Kg  = qkv + PSZ + HO;
  const unsigned short* Vtg = qkv + 2*PSZ + HO;   // [d][l], row stride 512

  const int t    = threadIdx.x;
  const int lane = t & 63;
  const int wave = t >> 6;
  const int quad = lane >> 4;
  const int ln   = lane & 15;

  // staging: unit u -> row u>>3, chunk u&7; fetch global chunk (u&7)^(row&7)
  const int u0 = t, u1 = t + 256;
  const int kr0 = u0 >> 3, kc0 = (u0 & 7) ^ (kr0 & 7);
  const int kr1 = u1 >> 3, kc1 = (u1 & 7) ^ (kr1 & 7);

  // Q fragments (A-layout) straight from global
  bf16x8 aq[2][2];
  #pragma unroll
  for (int rg = 0; rg < 2; ++rg){
    const int row = qt*128 + rg*64 + wave*16 + ln;
    #pragma unroll
    for (int ks = 0; ks < 2; ++ks)
      aq[rg][ks] = *(const bf16x8*)(Qg + (size_t)row*64 + ks*32 + quad*8);
  }

  const int ktEnd = 2*qt + 1;

  // prefetch kt=0
  __builtin_amdgcn_global_load_lds((gas_t)(Kg  + kr0*64  + kc0*8), (las_t)(Ks[0]  + u0*8), 16,0,0);
  __builtin_amdgcn_global_load_lds((gas_t)(Kg  + kr1*64  + kc1*8), (las_t)(Ks[0]  + u1*8), 16,0,0);
  __builtin_amdgcn_global_load_lds((gas_t)(Vtg + kr0*512 + kc0*8), (las_t)(Vts[0] + u0*8), 16,0,0);
  __builtin_amdgcn_global_load_lds((gas_t)(Vtg + kr1*512 + kc1*8), (las_t)(Vts[0] + u1*8), 16,0,0);

  float m_r[2][4], l_r[2][4];
  #pragma unroll
  for (int rg = 0; rg < 2; ++rg)
    #pragma unroll
    for (int r = 0; r < 4; ++r){ m_r[rg][r] = -3e38f; l_r[rg][r] = 0.f; }
  f32x4 o[2][4] = {};

  const int swzl = ln & 7;            // reader xor (row&7 == ln&7 for rows kn*16+ln / dn*16+ln)
  unsigned short* Pw = Ps[wave];
  const int rowoff = wave*16 + quad*4;

  for (int kt = 0; kt <= ktEnd; ++kt){
    __syncthreads();                  // drains kt's loads; protects other buffer's readers
    if (kt < ktEnd){
      const unsigned short* Kn  = Kg + (kt+1)*4096;
      const int col = (kt+1)*64;
      unsigned short* kb = Ks[(kt+1)&1];
      unsigned short* vb = Vts[(kt+1)&1];
      __builtin_amdgcn_global_load_lds((gas_t)(Kn  + kr0*64 + kc0*8),        (las_t)(kb + u0*8), 16,0,0);
      __builtin_amdgcn_global_load_lds((gas_t)(Kn  + kr1*64 + kc1*8),        (las_t)(kb + u1*8), 16,0,0);
      __builtin_amdgcn_global_load_lds((gas_t)(Vtg + kr0*512 + col + kc0*8), (las_t)(vb + u0*8), 16,0,0);
      __builtin_amdgcn_global_load_lds((gas_t)(Vtg + kr1*512 + col + kc1*8), (las_t)(vb + u1*8), 16,0,0);
    }
    const unsigned short* ks_ = Ks[kt&1];
    const unsigned short* vt_ = Vts[kt&1];

    #pragma unroll
    for (int rg = 0; rg < 2; ++rg){
      if (rg == 0 && kt > 2*qt) continue;       // rg0 fully masked only at kt==ktEnd
      const bool diag = (kt == 2*qt + rg);

      f32x4 s[4] = {};
      __builtin_amdgcn_s_setprio(1);
      #pragma unroll
      for (int ks2 = 0; ks2 < 2; ++ks2){
        #pragma unroll
        for (int kn = 0; kn < 4; ++kn){
          const bf16x8 bk = *(const bf16x8*)(ks_ + (kn*16+ln)*64 + (((quad + ks2*4) ^ swzl))*8);
          s[kn] = __builtin_amdgcn_mfma_f32_16x16x32_bf16(aq[rg][ks2], bk, s[kn], 0, 0, 0);
        }
      }
      __builtin_amdgcn_s_setprio(0);

      float p[4][4], lm[4] = {-3e38f,-3e38f,-3e38f,-3e38f};
      #pragma unroll
      for (int kn = 0; kn < 4; ++kn){
        const int col = kn*16 + ln;
        #pragma unroll
        for (int r = 0; r < 4; ++r){
          float v = s[kn][r] * 0.125f;
          if (diag && col > rowoff + r) v = -1e9f;
          p[kn][r] = v;
          lm[r] = fmaxf(lm[r], v);
        }
      }
      #pragma unroll
      for (int off = 1; off < 16; off <<= 1)
        #pragma unroll
        for (int r = 0; r < 4; ++r)
          lm[r] = fmaxf(lm[r], __shfl_xor(lm[r], off, 64));
      float alpha[4], rsum[4];
      #pragma unroll
      for (int r = 0; r < 4; ++r){
        const float mn = fmaxf(m_r[rg][r], lm[r]);
        alpha[r] = __expf(m_r[rg][r] - mn);
        m_r[rg][r] = mn;
      }
      #pragma unroll
      for (int kn = 0; kn < 4; ++kn)
        #pragma unroll
        for (int r = 0; r < 4; ++r)
          p[kn][r] = __expf(p[kn][r] - m_r[rg][r]);
      #pragma unroll
      for (int r = 0; r < 4; ++r)
        rsum[r] = (p[0][r] + p[1][r]) + (p[2][r] + p[3][r]);
      #pragma unroll
      for (int off = 1; off < 16; off <<= 1)
        #pragma unroll
        for (int r = 0; r < 4; ++r)
          rsum[r] += __shfl_xor(rsum[r], off, 64);
      #pragma unroll
      for (int r = 0; r < 4; ++r) l_r[rg][r] = l_r[rg][r]*alpha[r] + rsum[r];
      #pragma unroll
      for (int dn = 0; dn < 4; ++dn)
        #pragma unroll
        for (int r = 0; r < 4; ++r)
          o[rg][dn][r] *= alpha[r];

      // P: C-layout -> wave-local LDS [row-in-rg 0..31][key], A-layout source
      #pragma unroll
      for (int kn = 0; kn < 4; ++kn)
        #pragma unroll
        for (int r = 0; r < 4; ++r)
          Pw[(rg*16 + quad*4 + r)*PSTR + kn*16 + ln] = f2bf(p[kn][r]);

      __builtin_amdgcn_s_setprio(1);
      #pragma unroll
      for (int ks2 = 0; ks2 < 2; ++ks2){
        const bf16x8 ap = *(const bf16x8*)(Pw + (rg*16 + ln)*PSTR + quad*8 + ks2*32);
        #pragma unroll
        for (int dn = 0; dn < 4; ++dn){
          const bf16x8 bv = *(const bf16x8*)(vt_ + (dn*16+ln)*64 + (((quad + ks2*4) ^ swzl))*8);
          o[rg][dn] = __builtin_amdgcn_mfma_f32_16x16x32_bf16(ap, bv, o[rg][dn], 0, 0, 0);
        }
      }
      __builtin_amdgcn_s_setprio(0);
    }
  }

  #pragma unroll
  for (int rg = 0; rg < 2; ++rg){
    #pragma unroll
    for (int r = 0; r < 4; ++r){
      const float inv = 1.0f / l_r[rg][r];
      const int row = qt*128 + rg*64 + wave*16 + quad*4 + r;
      unsigned short* op = ctx + ((size_t)b*512 + row)*1024 + h*64 + ln;
      #pragma unroll
      for (int dn = 0; dn < 4; ++dn)
        op[dn*16] = f2bf(o[rg][dn][r] * inv);
    }
  }
}

// ---------------- launch ----------------

extern "C" void kernel_launch(void* const* d_in, const int* in_sizes, int n_in,
                              void* d_out, int out_size, void* d_ws, size_t ws_size,
                              hipStream_t stream) {
  const float* x     = (const float*)d_in[0];
  const float* qw    = (const float*)d_in[1];
  const float* kw    = (const float*)d_in[2];
  const float* vw    = (const float*)d_in[3];
  const float* ow    = (const float*)d_in[4];
  const float* rw    = (const float*)d_in[5];
  const float* rbias = (const float*)d_in[6];
  float* out = (float*)d_out;
  char* ws = (char*)d_ws;

  float* part            = (float*)(ws + OFF_PART);
  int* routes            = (int*)(ws + OFF_ROUTES);
  unsigned short* xb     = (unsigned short*)(ws + OFF_XB);
  unsigned short* wt     = (unsigned short*)(ws + OFF_WT);
  unsigned short* qkvbuf = (unsigned short*)(ws + OFF_QKV);
  unsigned short* ctx    = xb;
  float* probs = out + (size_t)32*512*1024;

  meanpool_kernel<<<dim3(32, 16), 256, 0, stream>>>(x, part, xb);
  router_kernel<<<32, 256, 0, stream>>>(part, rw, rbias, probs, routes);
  wcast_kernel<<<dim3(32, 32, 8), 256, 0, stream>>>(qw, wt);
  wcast_kernel<<<dim3(32, 32, 8), 256, 0, stream>>>(kw, wt + (size_t)8*1024*1024);
  wcast_kernel<<<dim3(32, 32, 8), 256, 0, stream>>>(vw, wt + (size_t)16*1024*1024);
  wcast_kernel<<<dim3(32, 32, 8), 256, 0, stream>>>(ow, wt + (size_t)24*1024*1024);
  gemm_kernel<0><<<dim3(8, 96), 512, 0, stream>>>(xb, wt, routes, qkvbuf, nullptr);
  attn_kernel<<<dim3(4, 16, 32), 256, 0, stream>>>(qkvbuf, ctx);
  gemm_kernel<1><<<dim3(8, 32), 512, 0, stream>>>(ctx, wt + (size_t)24*1024*1024, routes,
                                                  nullptr, out);
}

// Round 4
// 513.593 us; speedup vs baseline: 1.0200x; 1.0050x over previous
//
#include <hip/hip_runtime.h>

// RoutedSelfAttention on MI355X.
// meanpool+cast (vectorized) -> router (ILP reduce + wave shuffle) -> wcast (float4/ushort4
// 64x64 LDS transpose) -> MFMA GEMM qkv (256x256 tile, BK=64, 8 waves, 4-phase pipelined
// schedule, XCD-swizzled, cheap-RoPE epilogue, v written transposed)
// -> bf16 MFMA flash attention -> MFMA GEMM out.

typedef __attribute__((ext_vector_type(8))) short bf16x8;
typedef __attribute__((ext_vector_type(4))) float f32x4;

typedef const __attribute__((address_space(1))) unsigned short* gas_t;
typedef __attribute__((address_space(3))) unsigned short* las_t;

#define OFF_PART   (0ull)            // [32][16][1024] f32 partial mean sums (2 MB)
#define OFF_ROUTES (2ull << 20)      // [32] int
#define OFF_XB     (3ull << 20)      // x bf16 [32][512][1024] (32 MB); reused as ctx
#define OFF_WT     (40ull << 20)     // W^T bf16 [4][8][1024][1024] (64 MB)
#define OFF_QKV    (112ull << 20)    // q,k [p][32][16][512][64]; vT [32][16][64][512] (96 MB)

__device__ __forceinline__ unsigned short f2bf(float f){
  unsigned int u = __float_as_uint(f);
  u += 0x7fffu + ((u >> 16) & 1u);          // RNE
  return (unsigned short)(u >> 16);
}

// ---------------- meanpool fused with bf16 cast (float4 / ushort4) ----------------

__global__ void meanpool_kernel(const float* __restrict__ x, float* __restrict__ part,
                                unsigned short* __restrict__ xb){
  const int b = blockIdx.x, lc = blockIdx.y, t = threadIdx.x;
  const size_t base = ((size_t)b*512 + lc*32)*1024;
  const float* xs = x + base;
  unsigned short* xo = xb + base;
  float4 a = {0.f, 0.f, 0.f, 0.f};
  for (int l = 0; l < 32; ++l){
    const float4 v = *(const float4*)(xs + l*1024 + t*4);
    a.x += v.x; a.y += v.y; a.z += v.z; a.w += v.w;
    ushort4 pk;
    pk.x = f2bf(v.x); pk.y = f2bf(v.y); pk.z = f2bf(v.z); pk.w = f2bf(v.w);
    *(ushort4*)(xo + l*1024 + t*4) = pk;
  }
  *(float4*)(part + ((size_t)b*16 + lc)*1024 + t*4) = a;
}

// ---------------- router: ILP row-reduce + wave shuffle reduction ----------------

__global__ void router_kernel(const float* __restrict__ part,
                              const float* __restrict__ rw,
                              const float* __restrict__ rbias,
                              float* __restrict__ probs,
                              int* __restrict__ routes){
  const int b = blockIdx.x, t = threadIdx.x;
  const int lane = t & 63, wave = t >> 6;
  __shared__ float wred[4][8];
  float p[8] = {0.f,0.f,0.f,0.f,0.f,0.f,0.f,0.f};
  #pragma unroll
  for (int k = 0; k < 4; ++k){
    const int d = t + k*256;
    float s = 0.f;
    #pragma unroll
    for (int lc = 0; lc < 16; ++lc)             // 16 independent loads (ILP)
      s += part[((size_t)b*16 + lc)*1024 + d];
    s *= (1.0f/512.0f);
    const float4 w0 = *(const float4*)(rw + d*8);
    const float4 w1 = *(const float4*)(rw + d*8 + 4);
    p[0] = fmaf(s, w0.x, p[0]); p[1] = fmaf(s, w0.y, p[1]);
    p[2] = fmaf(s, w0.z, p[2]); p[3] = fmaf(s, w0.w, p[3]);
    p[4] = fmaf(s, w1.x, p[4]); p[5] = fmaf(s, w1.y, p[5]);
    p[6] = fmaf(s, w1.z, p[6]); p[7] = fmaf(s, w1.w, p[7]);
  }
  #pragma unroll
  for (int off = 1; off < 64; off <<= 1)
    #pragma unroll
    for (int e = 0; e < 8; ++e)
      p[e] += __shfl_xor(p[e], off, 64);
  if (lane == 0){
    #pragma unroll
    for (int e = 0; e < 8; ++e) wred[wave][e] = p[e];
  }
  __syncthreads();
  if (t == 0){
    float lg[8], mx = -3e38f; int am = 0;
    #pragma unroll
    for (int e = 0; e < 8; ++e){
      lg[e] = wred[0][e] + wred[1][e] + wred[2][e] + wred[3][e] + rbias[e];
      if (lg[e] > mx){ mx = lg[e]; am = e; }
    }
    float sum = 0.f, ex[8];
    #pragma unroll
    for (int e = 0; e < 8; ++e){ ex[e] = __expf(lg[e] - mx); sum += ex[e]; }
    const float inv = 1.0f / sum;
    #pragma unroll
    for (int e = 0; e < 8; ++e) probs[b*8 + e] = ex[e] * inv;
    routes[b] = am;
  }
}

// ---------------- weight transpose-cast: 64x64 tile, float4 in / ushort4 out ----------

__global__ void wcast_kernel(const float* __restrict__ W, unsigned short* __restrict__ Wt){
  __shared__ float tile[64][65];
  const int mtx = blockIdx.z;
  const float* Wm = W + (size_t)mtx*1024*1024;
  unsigned short* Wo = Wt + (size_t)mtx*1024*1024;
  const int t = threadIdx.x;
  const int r = t >> 4;          // 0..15
  const int c4 = t & 15;         // 0..15 (x4 cols)
  const int gx = blockIdx.x*64, gy = blockIdx.y*64;
  #pragma unroll
  for (int k = 0; k < 4; ++k){
    const int rr = r + 16*k;
    const float4 v = *(const float4*)(Wm + (size_t)(gy + rr)*1024 + gx + c4*4);
    tile[rr][c4*4+0] = v.x; tile[rr][c4*4+1] = v.y;
    tile[rr][c4*4+2] = v.z; tile[rr][c4*4+3] = v.w;
  }
  __syncthreads();
  #pragma unroll
  for (int k = 0; k < 4; ++k){
    const int rr = r + 16*k;
    ushort4 pk;
    pk.x = f2bf(tile[c4*4+0][rr]); pk.y = f2bf(tile[c4*4+1][rr]);
    pk.z = f2bf(tile[c4*4+2][rr]); pk.w = f2bf(tile[c4*4+3][rr]);
    *(ushort4*)(Wo + (size_t)(gx + rr)*1024 + gy + c4*4) = pk;
  }
}

// ---------------- bf16 MFMA GEMM, 256x256 tile, BK=64, 8 waves, phase pipeline --------
// (unchanged from round 3 — control for this round)
// MODE 0: A=xb[b], W=Wt[p*8+route]; p<2: RoPE -> q/k [p][b][h][l][d]; p==2: vT [b][h][d][l]
// MODE 1: A=ctx[b], W=Wt_o[route]; -> d_out fp32

template<int MODE>
__global__ __launch_bounds__(512, 2) void gemm_kernel(
    const unsigned short* __restrict__ A,
    const unsigned short* __restrict__ Wt,
    const int* __restrict__ routes,
    unsigned short* __restrict__ qkvout,
    float* __restrict__ outf)
{
  __shared__ __align__(16) unsigned short As[2][256*64];
  __shared__ __align__(16) unsigned short Bs[2][256*64];

  const int f = blockIdx.x + blockIdx.y*8;
  const int CH = (MODE == 0) ? 96 : 32;      // nwg/8
  const int wg = (f & 7)*CH + (f >> 3);
  const int slice = wg >> 3;
  const int tile  = wg & 7;
  const int m0 = (tile >> 2)*256;
  const int n0 = (tile & 3)*256;
  const int b = (MODE == 0) ? (slice/3) : slice;   // slice = b*3+p keeps A-panel adjacent
  const int p = (MODE == 0) ? (slice - b*3) : 0;

  const int route = routes[b];
  const unsigned short* Ab = A + (size_t)b*512*1024;
  const unsigned short* Wb = Wt + (size_t)((MODE == 0) ? (p*8 + route) : route)*1024*1024;

  const int t = threadIdx.x;
  const int lane = t & 63;
  const int wave = t >> 6;          // 0..7
  const int wm = (wave >> 2)*128;   // 2 waves in M
  const int wn = (wave & 3)*64;     // 4 waves in N
  const int quad = lane >> 4;
  const int ln = lane & 15;

  const int srow = t >> 3;
  const int sch  = (t & 7) ^ (srow & 7);
  const unsigned short* gA0 = Ab + (size_t)(m0 + srow)*1024 + sch*8;
  const unsigned short* gB0 = Wb + (size_t)(n0 + srow)*1024 + sch*8;

  const int w8 = ln & 7;
  const int aO0 = (wm + ln)*64 + ((quad    ) ^ w8)*8;
  const int aO1 = (wm + ln)*64 + ((quad + 4) ^ w8)*8;
  const int bO0 = (wn + ln)*64 + ((quad    ) ^ w8)*8;
  const int bO1 = (wn + ln)*64 + ((quad + 4) ^ w8)*8;

  f32x4 acc[8][4] = {};
  bf16x8 a0[4][2], a1[4][2], b01[2][2], b23[2][2];

#define STAGE(c_, T_) do { \
    const size_t ko_ = (size_t)(T_)*64; \
    las_t dA_ = (las_t)(&As[c_][0]) + (size_t)t*8; \
    las_t dB_ = (las_t)(&Bs[c_][0]) + (size_t)t*8; \
    _Pragma("unroll") \
    for (int k_ = 0; k_ < 4; ++k_){ \
      __builtin_amdgcn_global_load_lds((gas_t)(gA0 + ko_ + (size_t)k_*65536), dA_ + k_*4096, 16, 0, 0); \
      __builtin_amdgcn_global_load_lds((gas_t)(gB0 + ko_ + (size_t)k_*65536), dB_ + k_*4096, 16, 0, 0); \
    } \
  } while (0)

#define RD(ptr_, off_) (*(const bf16x8*)((ptr_) + (off_)))
#define READ_F0(pA_, pB_) do { \
    _Pragma("unroll") for (int f_ = 0; f_ < 4; ++f_){ \
      a0[f_][0] = RD(pA_, aO0 + f_*1024); a0[f_][1] = RD(pA_, aO1 + f_*1024); } \
    _Pragma("unroll") for (int f_ = 0; f_ < 2; ++f_){ \
      b01[f_][0] = RD(pB_, bO0 + f_*1024); b01[f_][1] = RD(pB_, bO1 + f_*1024); } \
  } while (0)
#define READ_F1(pA_) do { \
    _Pragma("unroll") for (int f_ = 0; f_ < 4; ++f_){ \
      a1[f_][0] = RD(pA_, aO0 + (4+f_)*1024); a1[f_][1] = RD(pA_, aO1 + (4+f_)*1024); } \
  } while (0)
#define READ_F2(pB_) do { \
    _Pragma("unroll") for (int f_ = 0; f_ < 2; ++f_){ \
      b23[f_][0] = RD(pB_, bO0 + (2+f_)*1024); b23[f_][1] = RD(pB_, bO1 + (2+f_)*1024); } \
  } while (0)

#define MSET(AF_, BF_, IB_, JB_) do { \
    _Pragma("unroll") for (int f_ = 0; f_ < 4; ++f_) \
    _Pragma("unroll") for (int n_ = 0; n_ < 2; ++n_) \
    _Pragma("unroll") for (int k_ = 0; k_ < 2; ++k_) \
      acc[IB_+f_][JB_+n_] = __builtin_amdgcn_mfma_f32_16x16x32_bf16( \
          AF_[f_][k_], BF_[n_][k_], acc[IB_+f_][JB_+n_], 0, 0, 0); \
  } while (0)

  STAGE(0, 0);
  STAGE(1, 1);
  asm volatile("s_waitcnt vmcnt(8)" ::: "memory");
  __builtin_amdgcn_s_barrier();
  READ_F0((&As[0][0]), (&Bs[0][0]));

  for (int g = 0; g < 16; ++g){
    const int c = g & 1;
    const unsigned short* pA  = &As[c][0];
    const unsigned short* pB  = &Bs[c][0];
    const unsigned short* pAn = &As[c ^ 1][0];
    const unsigned short* pBn = &Bs[c ^ 1][0];

    READ_F1(pA);
    __builtin_amdgcn_s_barrier();
    asm volatile("s_waitcnt lgkmcnt(8)" ::: "memory");
    __builtin_amdgcn_sched_barrier(0);
    __builtin_amdgcn_s_setprio(1);
    MSET(a0, b01, 0, 0);
    __builtin_amdgcn_s_setprio(0);
    __builtin_amdgcn_s_barrier();

    READ_F2(pB);
    __builtin_amdgcn_s_barrier();
    asm volatile("s_waitcnt lgkmcnt(4)" ::: "memory");
    __builtin_amdgcn_sched_barrier(0);
    __builtin_amdgcn_s_setprio(1);
    MSET(a1, b01, 4, 0);
    __builtin_amdgcn_s_setprio(0);
    __builtin_amdgcn_s_barrier();

    asm volatile("s_waitcnt lgkmcnt(0)" ::: "memory");
    __builtin_amdgcn_sched_barrier(0);
    __builtin_amdgcn_s_setprio(1);
    MSET(a1, b23, 4, 2);
    __builtin_amdgcn_s_setprio(0);
    __builtin_amdgcn_s_barrier();

    if (g < 14){
      STAGE(c, g + 2);
      asm volatile("s_waitcnt vmcnt(8)" ::: "memory");
    } else if (g == 14){
      asm volatile("s_waitcnt vmcnt(0)" ::: "memory");
    }
    __builtin_amdgcn_s_barrier();
    __builtin_amdgcn_s_setprio(1);
    MSET(a0, b23, 0, 2);
    __builtin_amdgcn_s_setprio(0);
    if (g < 15) READ_F0(pAn, pBn);
    __builtin_amdgcn_s_barrier();
  }
#undef STAGE
#undef RD
#undef READ_F0
#undef READ_F1
#undef READ_F2
#undef MSET

  if (MODE == 0){
    const size_t PSZ = (size_t)32*16*512*64;
    if (p < 2){
      #pragma unroll
      for (int fn = 0; fn < 4; ++fn){
        const int e  = n0 + wn + fn*16 + ln;
        const int h  = e >> 6;
        const int eh = e & 63;
        const float invf = exp2f(-0.41524101f * (float)(eh >> 1)); // 10000^(-2i/64)
        float s1, c1; __sincosf(invf, &s1, &c1);
        unsigned short* outp = qkvout + ((((size_t)p*32 + b)*16 + h)*512)*64 + eh;
        #pragma unroll
        for (int fm = 0; fm < 8; ++fm){
          const int l0 = m0 + wm + fm*16 + quad*4;
          float sn, cs;
          __sincosf((float)l0 * invf, &sn, &cs);
          #pragma unroll
          for (int r = 0; r < 4; ++r){
            const int l = l0 + r;
            const float own = acc[fm][fn][r];
            const float par = __shfl_xor(own, 1, 64);
            const float v = (e & 1) ? fmaf(own, cs, par*sn) : fmaf(own, cs, -par*sn);
            outp[(size_t)l*64] = f2bf(v);
            const float nc = cs*c1 - sn*s1;     // rotate angle by +invf
            const float ns = sn*c1 + cs*s1;
            cs = nc; sn = ns;
          }
        }
      }
    } else {
      #pragma unroll
      for (int fn = 0; fn < 4; ++fn){
        const int e  = n0 + wn + fn*16 + ln;
        const int h  = e >> 6;
        const int eh = e & 63;
        unsigned short* outp = qkvout + 2*PSZ + (((size_t)b*16 + h)*64 + eh)*512;
        #pragma unroll
        for (int fm = 0; fm < 8; ++fm){
          const int l0 = m0 + wm + fm*16 + quad*4;
          ushort4 pk;
          pk.x = f2bf(acc[fm][fn][0]); pk.y = f2bf(acc[fm][fn][1]);
          pk.z = f2bf(acc[fm][fn][2]); pk.w = f2bf(acc[fm][fn][3]);
          *(ushort4*)(outp + l0) = pk;
        }
      }
    }
  } else {
    #pragma unroll
    for (int fn = 0; fn < 4; ++fn){
      const int e = n0 + wn + fn*16 + ln;
      #pragma unroll
      for (int fm = 0; fm < 8; ++fm){
        #pragma unroll
        for (int r = 0; r < 4; ++r){
          const int l = m0 + wm + fm*16 + quad*4 + r;
          outf[((size_t)b*512 + l)*1024 + e] = acc[fm][fn][r];
        }
      }
    }
  }
}

// ---------------- bf16 MFMA flash attention, 128-row Q blocks (unchanged) ----------------

#define PSTR 72

__global__ __launch_bounds__(256, 3) void attn_kernel(
    const unsigned short* __restrict__ qkv,
    unsigned short* __restrict__ ctx)
{
  __shared__ __align__(16) unsigned short Ks[2][64*64];
  __shared__ __align__(16) unsigned short Vts[2][64*64];
  __shared__ __align__(16) unsigned short Ps[4][32*PSTR];

  int wg = blockIdx.x + (blockIdx.y << 2) + (blockIdx.z << 6);
  wg = (wg & 7) * 256 + (wg >> 3);
  const int b  = wg >> 6;
  const int h  = (wg >> 2) & 15;
  const int qt = wg & 3;

  const size_t HO  = (((size_t)b)*16 + h)*512*64;
  const size_t PSZ = (size_t)32*16*512*64;
  const unsigned short* Qg  = qkv + HO;
  const unsigned short* Kg  = qkv + PSZ + HO;
  const unsigned short* Vtg = qkv + 2*PSZ + HO;   // [d][l], row stride 512

  const int t    = threadIdx.x;
  const int lane = t & 63;
  const int wave = t >> 6;
  const int quad = lane >> 4;
  const int ln   = lane & 15;

  const int u0 = t, u1 = t + 256;
  const int kr0 = u0 >> 3, kc0 = (u0 & 7) ^ (kr0 & 7);
  const int kr1 = u1 >> 3, kc1 = (u1 & 7) ^ (kr1 & 7);

  bf16x8 aq[2][2];
  #pragma unroll
  for (int rg = 0; rg < 2; ++rg){
    const int row = qt*128 + rg*64 + wave*16 + ln;
    #pragma unroll
    for (int ks = 0; ks < 2; ++ks)
      aq[rg][ks] = *(const bf16x8*)(Qg + (size_t)row*64 + ks*32 + quad*8);
  }

  const int ktEnd = 2*qt + 1;

  __builtin_amdgcn_global_load_lds((gas_t)(Kg  + kr0*64  + kc0*8), (las_t)(Ks[0]  + u0*8), 16,0,0);
  __builtin_amdgcn_global_load_lds((gas_t)(Kg  + kr1*64  + kc1*8), (las_t)(Ks[0]  + u1*8), 16,0,0);
  __builtin_amdgcn_global_load_lds((gas_t)(Vtg + kr0*512 + kc0*8), (las_t)(Vts[0] + u0*8), 16,0,0);
  __builtin_amdgcn_global_load_lds((gas_t)(Vtg + kr1*512 + kc1*8), (las_t)(Vts[0] + u1*8), 16,0,0);

  float m_r[2][4], l_r[2][4];
  #pragma unroll
  for (int rg = 0; rg < 2; ++rg)
    #pragma unroll
    for (int r = 0; r < 4; ++r){ m_r[rg][r] = -3e38f; l_r[rg][r] = 0.f; }
  f32x4 o[2][4] = {};

  const int swzl = ln & 7;
  unsigned short* Pw = Ps[wave];
  const int rowoff = wave*16 + quad*4;

  for (int kt = 0; kt <= ktEnd; ++kt){
    __syncthreads();
    if (kt < ktEnd){
      const unsigned short* Kn  = Kg + (kt+1)*4096;
      const int col = (kt+1)*64;
      unsigned short* kb = Ks[(kt+1)&1];
      unsigned short* vb = Vts[(kt+1)&1];
      __builtin_amdgcn_global_load_lds((gas_t)(Kn  + kr0*64 + kc0*8),        (las_t)(kb + u0*8), 16,0,0);
      __builtin_amdgcn_global_load_lds((gas_t)(Kn  + kr1*64 + kc1*8),        (las_t)(kb + u1*8), 16,0,0);
      __builtin_amdgcn_global_load_lds((gas_t)(Vtg + kr0*512 + col + kc0*8), (las_t)(vb + u0*8), 16,0,0);
      __builtin_amdgcn_global_load_lds((gas_t)(Vtg + kr1*512 + col + kc1*8), (las_t)(vb + u1*8), 16,0,0);
    }
    const unsigned short* ks_ = Ks[kt&1];
    const unsigned short* vt_ = Vts[kt&1];

    #pragma unroll
    for (int rg = 0; rg < 2; ++rg){
      if (rg == 0 && kt > 2*qt) continue;
      const bool diag = (kt == 2*qt + rg);

      f32x4 s[4] = {};
      __builtin_amdgcn_s_setprio(1);
      #pragma unroll
      for (int ks2 = 0; ks2 < 2; ++ks2){
        #pragma unroll
        for (int kn = 0; kn < 4; ++kn){
          const bf16x8 bk = *(const bf16x8*)(ks_ + (kn*16+ln)*64 + (((quad + ks2*4) ^ swzl))*8);
          s[kn] = __builtin_amdgcn_mfma_f32_16x16x32_bf16(aq[rg][ks2], bk, s[kn], 0, 0, 0);
        }
      }
      __builtin_amdgcn_s_setprio(0);

      float p[4][4], lm[4] = {-3e38f,-3e38f,-3e38f,-3e38f};
      #pragma unroll
      for (int kn = 0; kn < 4; ++kn){
        const int col = kn*16 + ln;
        #pragma unroll
        for (int r = 0; r < 4; ++r){
          float v = s[kn][r] * 0.125f;
          if (diag && col > rowoff + r) v = -1e9f;
          p[kn][r] = v;
          lm[r] = fmaxf(lm[r], v);
        }
      }
      #pragma unroll
      for (int off = 1; off < 16; off <<= 1)
        #pragma unroll
        for (int r = 0; r < 4; ++r)
          lm[r] = fmaxf(lm[r], __shfl_xor(lm[r], off, 64));
      float alpha[4], rsum[4];
      #pragma unroll
      for (int r = 0; r < 4; ++r){
        const float mn = fmaxf(m_r[rg][r], lm[r]);
        alpha[r] = __expf(m_r[rg][r] - mn);
        m_r[rg][r] = mn;
      }
      #pragma unroll
      for (int kn = 0; kn < 4; ++kn)
        #pragma unroll
        for (int r = 0; r < 4; ++r)
          p[kn][r] = __expf(p[kn][r] - m_r[rg][r]);
      #pragma unroll
      for (int r = 0; r < 4; ++r)
        rsum[r] = (p[0][r] + p[1][r]) + (p[2][r] + p[3][r]);
      #pragma unroll
      for (int off = 1; off < 16; off <<= 1)
        #pragma unroll
        for (int r = 0; r < 4; ++r)
          rsum[r] += __shfl_xor(rsum[r], off, 64);
      #pragma unroll
      for (int r = 0; r < 4; ++r) l_r[rg][r] = l_r[rg][r]*alpha[r] + rsum[r];
      #pragma unroll
      for (int dn = 0; dn < 4; ++dn)
        #pragma unroll
        for (int r = 0; r < 4; ++r)
          o[rg][dn][r] *= alpha[r];

      #pragma unroll
      for (int kn = 0; kn < 4; ++kn)
        #pragma unroll
        for (int r = 0; r < 4; ++r)
          Pw[(rg*16 + quad*4 + r)*PSTR + kn*16 + ln] = f2bf(p[kn][r]);

      __builtin_amdgcn_s_setprio(1);
      #pragma unroll
      for (int ks2 = 0; ks2 < 2; ++ks2){
        const bf16x8 ap = *(const bf16x8*)(Pw + (rg*16 + ln)*PSTR + quad*8 + ks2*32);
        #pragma unroll
        for (int dn = 0; dn < 4; ++dn){
          const bf16x8 bv = *(const bf16x8*)(vt_ + (dn*16+ln)*64 + (((quad + ks2*4) ^ swzl))*8);
          o[rg][dn] = __builtin_amdgcn_mfma_f32_16x16x32_bf16(ap, bv, o[rg][dn], 0, 0, 0);
        }
      }
      __builtin_amdgcn_s_setprio(0);
    }
  }

  #pragma unroll
  for (int rg = 0; rg < 2; ++rg){
    #pragma unroll
    for (int r = 0; r < 4; ++r){
      const float inv = 1.0f / l_r[rg][r];
      const int row = qt*128 + rg*64 + wave*16 + quad*4 + r;
      unsigned short* op = ctx + ((size_t)b*512 + row)*1024 + h*64 + ln;
      #pragma unroll
      for (int dn = 0; dn < 4; ++dn)
        op[dn*16] = f2bf(o[rg][dn][r] * inv);
    }
  }
}

// ---------------- launch ----------------

extern "C" void kernel_launch(void* const* d_in, const int* in_sizes, int n_in,
                              void* d_out, int out_size, void* d_ws, size_t ws_size,
                              hipStream_t stream) {
  const float* x     = (const float*)d_in[0];
  const float* qw    = (const float*)d_in[1];
  const float* kw    = (const float*)d_in[2];
  const float* vw    = (const float*)d_in[3];
  const float* ow    = (const float*)d_in[4];
  const float* rw    = (const float*)d_in[5];
  const float* rbias = (const float*)d_in[6];
  float* out = (float*)d_out;
  char* ws = (char*)d_ws;

  float* part            = (float*)(ws + OFF_PART);
  int* routes            = (int*)(ws + OFF_ROUTES);
  unsigned short* xb     = (unsigned short*)(ws + OFF_XB);
  unsigned short* wt     = (unsigned short*)(ws + OFF_WT);
  unsigned short* qkvbuf = (unsigned short*)(ws + OFF_QKV);
  unsigned short* ctx    = xb;
  float* probs = out + (size_t)32*512*1024;

  meanpool_kernel<<<dim3(32, 16), 256, 0, stream>>>(x, part, xb);
  router_kernel<<<32, 256, 0, stream>>>(part, rw, rbias, probs, routes);
  wcast_kernel<<<dim3(16, 16, 8), 256, 0, stream>>>(qw, wt);
  wcast_kernel<<<dim3(16, 16, 8), 256, 0, stream>>>(kw, wt + (size_t)8*1024*1024);
  wcast_kernel<<<dim3(16, 16, 8), 256, 0, stream>>>(vw, wt + (size_t)16*1024*1024);
  wcast_kernel<<<dim3(16, 16, 8), 256, 0, stream>>>(ow, wt + (size_t)24*1024*1024);
  gemm_kernel<0><<<dim3(8, 96), 512, 0, stream>>>(xb, wt, routes, qkvbuf, nullptr);
  attn_kernel<<<dim3(4, 16, 32), 256, 0, stream>>>(qkvbuf, ctx);
  gemm_kernel<1><<<dim3(8, 32), 512, 0, stream>>>(ctx, wt + (size_t)24*1024*1024, routes,
                                                  nullptr, out);
}

// Round 5
// 509.912 us; speedup vs baseline: 1.0274x; 1.0072x over previous
//
#include <hip/hip_runtime.h>

// RoutedSelfAttention on MI355X.
// meanpool+cast (vectorized) -> router (ILP reduce + wave shuffle) -> wcast (float4/ushort4
// 64x64 LDS transpose) -> MFMA GEMM qkv (256x256 tile, BK=64, 8 waves, 4-phase pipelined
// schedule, XCD-swizzled; e = wn + ln*4 + fn column mapping -> ushort4/float4 full-line
// epilogue stores + lane-local RoPE) -> bf16 MFMA flash attention -> MFMA GEMM out.

typedef __attribute__((ext_vector_type(8))) short bf16x8;
typedef __attribute__((ext_vector_type(4))) float f32x4;

typedef const __attribute__((address_space(1))) unsigned short* gas_t;
typedef __attribute__((address_space(3))) unsigned short* las_t;

#define OFF_PART   (0ull)            // [32][16][1024] f32 partial mean sums (2 MB)
#define OFF_ROUTES (2ull << 20)      // [32] int
#define OFF_XB     (3ull << 20)      // x bf16 [32][512][1024] (32 MB); reused as ctx
#define OFF_WT     (40ull << 20)     // W^T bf16 [4][8][1024][1024] (64 MB)
#define OFF_QKV    (112ull << 20)    // q,k [p][32][16][512][64]; vT [32][16][64][512] (96 MB)

__device__ __forceinline__ unsigned short f2bf(float f){
  unsigned int u = __float_as_uint(f);
  u += 0x7fffu + ((u >> 16) & 1u);          // RNE
  return (unsigned short)(u >> 16);
}

// ---------------- meanpool fused with bf16 cast (float4 / ushort4) ----------------

__global__ void meanpool_kernel(const float* __restrict__ x, float* __restrict__ part,
                                unsigned short* __restrict__ xb){
  const int b = blockIdx.x, lc = blockIdx.y, t = threadIdx.x;
  const size_t base = ((size_t)b*512 + lc*32)*1024;
  const float* xs = x + base;
  unsigned short* xo = xb + base;
  float4 a = {0.f, 0.f, 0.f, 0.f};
  for (int l = 0; l < 32; ++l){
    const float4 v = *(const float4*)(xs + l*1024 + t*4);
    a.x += v.x; a.y += v.y; a.z += v.z; a.w += v.w;
    ushort4 pk;
    pk.x = f2bf(v.x); pk.y = f2bf(v.y); pk.z = f2bf(v.z); pk.w = f2bf(v.w);
    *(ushort4*)(xo + l*1024 + t*4) = pk;
  }
  *(float4*)(part + ((size_t)b*16 + lc)*1024 + t*4) = a;
}

// ---------------- router: ILP row-reduce + wave shuffle reduction ----------------

__global__ void router_kernel(const float* __restrict__ part,
                              const float* __restrict__ rw,
                              const float* __restrict__ rbias,
                              float* __restrict__ probs,
                              int* __restrict__ routes){
  const int b = blockIdx.x, t = threadIdx.x;
  const int lane = t & 63, wave = t >> 6;
  __shared__ float wred[4][8];
  float p[8] = {0.f,0.f,0.f,0.f,0.f,0.f,0.f,0.f};
  #pragma unroll
  for (int k = 0; k < 4; ++k){
    const int d = t + k*256;
    float s = 0.f;
    #pragma unroll
    for (int lc = 0; lc < 16; ++lc)             // 16 independent loads (ILP)
      s += part[((size_t)b*16 + lc)*1024 + d];
    s *= (1.0f/512.0f);
    const float4 w0 = *(const float4*)(rw + d*8);
    const float4 w1 = *(const float4*)(rw + d*8 + 4);
    p[0] = fmaf(s, w0.x, p[0]); p[1] = fmaf(s, w0.y, p[1]);
    p[2] = fmaf(s, w0.z, p[2]); p[3] = fmaf(s, w0.w, p[3]);
    p[4] = fmaf(s, w1.x, p[4]); p[5] = fmaf(s, w1.y, p[5]);
    p[6] = fmaf(s, w1.z, p[6]); p[7] = fmaf(s, w1.w, p[7]);
  }
  #pragma unroll
  for (int off = 1; off < 64; off <<= 1)
    #pragma unroll
    for (int e = 0; e < 8; ++e)
      p[e] += __shfl_xor(p[e], off, 64);
  if (lane == 0){
    #pragma unroll
    for (int e = 0; e < 8; ++e) wred[wave][e] = p[e];
  }
  __syncthreads();
  if (t == 0){
    float lg[8], mx = -3e38f; int am = 0;
    #pragma unroll
    for (int e = 0; e < 8; ++e){
      lg[e] = wred[0][e] + wred[1][e] + wred[2][e] + wred[3][e] + rbias[e];
      if (lg[e] > mx){ mx = lg[e]; am = e; }
    }
    float sum = 0.f, ex[8];
    #pragma unroll
    for (int e = 0; e < 8; ++e){ ex[e] = __expf(lg[e] - mx); sum += ex[e]; }
    const float inv = 1.0f / sum;
    #pragma unroll
    for (int e = 0; e < 8; ++e) probs[b*8 + e] = ex[e] * inv;
    routes[b] = am;
  }
}

// ---------------- weight transpose-cast: 64x64 tile, float4 in / ushort4 out ----------

__global__ void wcast_kernel(const float* __restrict__ W, unsigned short* __restrict__ Wt){
  __shared__ float tile[64][65];
  const int mtx = blockIdx.z;
  const float* Wm = W + (size_t)mtx*1024*1024;
  unsigned short* Wo = Wt + (size_t)mtx*1024*1024;
  const int t = threadIdx.x;
  const int r = t >> 4;          // 0..15
  const int c4 = t & 15;         // 0..15 (x4 cols)
  const int gx = blockIdx.x*64, gy = blockIdx.y*64;
  #pragma unroll
  for (int k = 0; k < 4; ++k){
    const int rr = r + 16*k;
    const float4 v = *(const float4*)(Wm + (size_t)(gy + rr)*1024 + gx + c4*4);
    tile[rr][c4*4+0] = v.x; tile[rr][c4*4+1] = v.y;
    tile[rr][c4*4+2] = v.z; tile[rr][c4*4+3] = v.w;
  }
  __syncthreads();
  #pragma unroll
  for (int k = 0; k < 4; ++k){
    const int rr = r + 16*k;
    ushort4 pk;
    pk.x = f2bf(tile[c4*4+0][rr]); pk.y = f2bf(tile[c4*4+1][rr]);
    pk.z = f2bf(tile[c4*4+2][rr]); pk.w = f2bf(tile[c4*4+3][rr]);
    *(ushort4*)(Wo + (size_t)(gx + rr)*1024 + gy + c4*4) = pk;
  }
}

// ---------------- bf16 MFMA GEMM, 256x256 tile, BK=64, 8 waves, phase pipeline --------
// Output-column mapping: n-tile fn, lane ln -> e = n0 + wn + ln*4 + fn. Each lane owns 4
// consecutive e -> ushort4 (q/k/vT) or float4 (out) stores; 16 ln-lanes = 128/256 B dense
// (full HBM lines, no partial-line RMW). RoPE pairs (2i,2i+1) are lane-local (fn parity).
// B-frag LDS rows wn+ln*4+fn; B swizzle slot = chunk ^ ((row>>2)&7) -> reader xor = ln&7.
// MODE 0: A=xb[b], W=Wt[p*8+route]; p<2: RoPE -> q/k [p][b][h][l][d]; p==2: vT [b][h][d][l]
// MODE 1: A=ctx[b], W=Wt_o[route]; -> d_out fp32

template<int MODE>
__global__ __launch_bounds__(512, 2) void gemm_kernel(
    const unsigned short* __restrict__ A,
    const unsigned short* __restrict__ Wt,
    const int* __restrict__ routes,
    unsigned short* __restrict__ qkvout,
    float* __restrict__ outf)
{
  __shared__ __align__(16) unsigned short As[2][256*64];
  __shared__ __align__(16) unsigned short Bs[2][256*64];

  const int f = blockIdx.x + blockIdx.y*8;
  const int CH = (MODE == 0) ? 96 : 32;      // nwg/8
  const int wg = (f & 7)*CH + (f >> 3);
  const int slice = wg >> 3;
  const int tile  = wg & 7;
  const int m0 = (tile >> 2)*256;
  const int n0 = (tile & 3)*256;
  const int b = (MODE == 0) ? (slice/3) : slice;   // slice = b*3+p keeps A-panel adjacent
  const int p = (MODE == 0) ? (slice - b*3) : 0;

  const int route = routes[b];
  const unsigned short* Ab = A + (size_t)b*512*1024;
  const unsigned short* Wb = Wt + (size_t)((MODE == 0) ? (p*8 + route) : route)*1024*1024;

  const int t = threadIdx.x;
  const int lane = t & 63;
  const int wave = t >> 6;          // 0..7
  const int wm = (wave >> 2)*128;   // 2 waves in M
  const int wn = (wave & 3)*64;     // 4 waves in N
  const int quad = lane >> 4;
  const int ln = lane & 15;

  // staging: unit u=t (+k_*512); row = k_*64 + (t>>3); A slot xor = row&7 -> (t>>3)&7;
  // B slot xor = (row>>2)&7 -> (t>>5)&7 (both k_-invariant since 64,16 are mult of 8).
  const int srow = t >> 3;
  const int schA = (t & 7) ^ (srow & 7);
  const int schB = (t & 7) ^ ((t >> 5) & 7);
  const unsigned short* gA0 = Ab + (size_t)(m0 + srow)*1024 + schA*8;
  const unsigned short* gB0 = Wb + (size_t)(n0 + srow)*1024 + schB*8;

  // reader offsets (elems): A rows wm+f*16+ln (xor ln&7); B rows wn+ln*4+fn (xor ln&7,
  // since ((wn+ln*4+fn)>>2)&7 == ln&7 for wn multiple of 64, fn<4).
  const int w8 = ln & 7;
  const int aO0 = (wm + ln)*64 + ((quad    ) ^ w8)*8;
  const int aO1 = (wm + ln)*64 + ((quad + 4) ^ w8)*8;
  const int bO0 = (wn + ln*4)*64 + ((quad    ) ^ w8)*8;
  const int bO1 = (wn + ln*4)*64 + ((quad + 4) ^ w8)*8;

  f32x4 acc[8][4] = {};
  bf16x8 a0[4][2], a1[4][2], b01[2][2], b23[2][2];

#define STAGE(c_, T_) do { \
    const size_t ko_ = (size_t)(T_)*64; \
    las_t dA_ = (las_t)(&As[c_][0]) + (size_t)t*8; \
    las_t dB_ = (las_t)(&Bs[c_][0]) + (size_t)t*8; \
    _Pragma("unroll") \
    for (int k_ = 0; k_ < 4; ++k_){ \
      __builtin_amdgcn_global_load_lds((gas_t)(gA0 + ko_ + (size_t)k_*65536), dA_ + k_*4096, 16, 0, 0); \
      __builtin_amdgcn_global_load_lds((gas_t)(gB0 + ko_ + (size_t)k_*65536), dB_ + k_*4096, 16, 0, 0); \
    } \
  } while (0)

#define RD(ptr_, off_) (*(const bf16x8*)((ptr_) + (off_)))
#define READ_F0(pA_, pB_) do { \
    _Pragma("unroll") for (int f_ = 0; f_ < 4; ++f_){ \
      a0[f_][0] = RD(pA_, aO0 + f_*1024); a0[f_][1] = RD(pA_, aO1 + f_*1024); } \
    _Pragma("unroll") for (int f_ = 0; f_ < 2; ++f_){ \
      b01[f_][0] = RD(pB_, bO0 + f_*64); b01[f_][1] = RD(pB_, bO1 + f_*64); } \
  } while (0)
#define READ_F1(pA_) do { \
    _Pragma("unroll") for (int f_ = 0; f_ < 4; ++f_){ \
      a1[f_][0] = RD(pA_, aO0 + (4+f_)*1024); a1[f_][1] = RD(pA_, aO1 + (4+f_)*1024); } \
  } while (0)
#define READ_F2(pB_) do { \
    _Pragma("unroll") for (int f_ = 0; f_ < 2; ++f_){ \
      b23[f_][0] = RD(pB_, bO0 + (2+f_)*64); b23[f_][1] = RD(pB_, bO1 + (2+f_)*64); } \
  } while (0)

#define MSET(AF_, BF_, IB_, JB_) do { \
    _Pragma("unroll") for (int f_ = 0; f_ < 4; ++f_) \
    _Pragma("unroll") for (int n_ = 0; n_ < 2; ++n_) \
    _Pragma("unroll") for (int k_ = 0; k_ < 2; ++k_) \
      acc[IB_+f_][JB_+n_] = __builtin_amdgcn_mfma_f32_16x16x32_bf16( \
          AF_[f_][k_], BF_[n_][k_], acc[IB_+f_][JB_+n_], 0, 0, 0); \
  } while (0)

  STAGE(0, 0);
  STAGE(1, 1);
  asm volatile("s_waitcnt vmcnt(8)" ::: "memory");
  __builtin_amdgcn_s_barrier();
  READ_F0((&As[0][0]), (&Bs[0][0]));

  for (int g = 0; g < 16; ++g){
    const int c = g & 1;
    const unsigned short* pA  = &As[c][0];
    const unsigned short* pB  = &Bs[c][0];
    const unsigned short* pAn = &As[c ^ 1][0];
    const unsigned short* pBn = &Bs[c ^ 1][0];

    READ_F1(pA);
    __builtin_amdgcn_s_barrier();
    asm volatile("s_waitcnt lgkmcnt(8)" ::: "memory");
    __builtin_amdgcn_sched_barrier(0);
    __builtin_amdgcn_s_setprio(1);
    MSET(a0, b01, 0, 0);
    __builtin_amdgcn_s_setprio(0);
    __builtin_amdgcn_s_barrier();

    READ_F2(pB);
    __builtin_amdgcn_s_barrier();
    asm volatile("s_waitcnt lgkmcnt(4)" ::: "memory");
    __builtin_amdgcn_sched_barrier(0);
    __builtin_amdgcn_s_setprio(1);
    MSET(a1, b01, 4, 0);
    __builtin_amdgcn_s_setprio(0);
    __builtin_amdgcn_s_barrier();

    asm volatile("s_waitcnt lgkmcnt(0)" ::: "memory");
    __builtin_amdgcn_sched_barrier(0);
    __builtin_amdgcn_s_setprio(1);
    MSET(a1, b23, 4, 2);
    __builtin_amdgcn_s_setprio(0);
    __builtin_amdgcn_s_barrier();

    if (g < 14){
      STAGE(c, g + 2);
      asm volatile("s_waitcnt vmcnt(8)" ::: "memory");
    } else if (g == 14){
      asm volatile("s_waitcnt vmcnt(0)" ::: "memory");
    }
    __builtin_amdgcn_s_barrier();
    __builtin_amdgcn_s_setprio(1);
    MSET(a0, b23, 0, 2);
    __builtin_amdgcn_s_setprio(0);
    if (g < 15) READ_F0(pAn, pBn);
    __builtin_amdgcn_s_barrier();
  }
#undef STAGE
#undef RD
#undef READ_F0
#undef READ_F1
#undef READ_F2
#undef MSET

  if (MODE == 0){
    const size_t PSZ = (size_t)32*16*512*64;
    const int h = (n0 + wn) >> 6;       // wave's 64-e block = exactly one head
    if (p < 2){
      // lane-local RoPE: lane owns e = {4ln, 4ln+1, 4ln+2, 4ln+3} within the head;
      // pairs (fn0,fn1) at freq i0=2ln, (fn2,fn3) at i1=2ln+1. Angle-addition rotation
      // across the 4 consecutive positions r. Full 128-B-per-ln-group ushort4 stores.
      const int eh0 = ln*4;
      const float invf0 = exp2f(-0.41524101f * (float)(ln*2)); // 10000^(-2i/64)
      const float invf1 = invf0 * 0.74989420832f;              // * 10000^(-1/32)
      float sc0, cc0, sc1, cc1;
      __sincosf(invf0, &sc0, &cc0);
      __sincosf(invf1, &sc1, &cc1);
      unsigned short* outp = qkvout + ((((size_t)p*32 + b)*16 + h)*512)*64 + eh0;
      #pragma unroll
      for (int fm = 0; fm < 8; ++fm){
        const int l0 = m0 + wm + fm*16 + quad*4;
        float s0, c0, s1, c1;
        __sincosf((float)l0 * invf0, &s0, &c0);
        __sincosf((float)l0 * invf1, &s1, &c1);
        #pragma unroll
        for (int r = 0; r < 4; ++r){
          const int l = l0 + r;
          const float x0 = acc[fm][0][r], x1 = acc[fm][1][r];
          const float x2 = acc[fm][2][r], x3 = acc[fm][3][r];
          ushort4 pk;
          pk.x = f2bf(x0*c0 - x1*s0);
          pk.y = f2bf(x1*c0 + x0*s0);
          pk.z = f2bf(x2*c1 - x3*s1);
          pk.w = f2bf(x3*c1 + x2*s1);
          *(ushort4*)(outp + (size_t)l*64) = pk;
          const float nc0 = c0*cc0 - s0*sc0, ns0 = s0*cc0 + c0*sc0;
          const float nc1 = c1*cc1 - s1*sc1, ns1 = s1*cc1 + c1*sc1;
          c0 = nc0; s0 = ns0; c1 = nc1; s1 = ns1;
        }
      }
    } else {
      // vT[b][h][d][l]: pack 4 consecutive l (r=0..3) into one 8B store
      #pragma unroll
      for (int fn = 0; fn < 4; ++fn){
        const int eh = ln*4 + fn;
        unsigned short* outp = qkvout + 2*PSZ + (((size_t)b*16 + h)*64 + eh)*512;
        #pragma unroll
        for (int fm = 0; fm < 8; ++fm){
          const int l0 = m0 + wm + fm*16 + quad*4;
          ushort4 pk;
          pk.x = f2bf(acc[fm][fn][0]); pk.y = f2bf(acc[fm][fn][1]);
          pk.z = f2bf(acc[fm][fn][2]); pk.w = f2bf(acc[fm][fn][3]);
          *(ushort4*)(outp + l0) = pk;
        }
      }
    }
  } else {
    const int e0 = n0 + wn + ln*4;
    #pragma unroll
    for (int fm = 0; fm < 8; ++fm){
      #pragma unroll
      for (int r = 0; r < 4; ++r){
        const int l = m0 + wm + fm*16 + quad*4 + r;
        float4 f4;
        f4.x = acc[fm][0][r]; f4.y = acc[fm][1][r];
        f4.z = acc[fm][2][r]; f4.w = acc[fm][3][r];
        *(float4*)(outf + ((size_t)b*512 + l)*1024 + e0) = f4;
      }
    }
  }
}

// ---------------- bf16 MFMA flash attention, 128-row Q blocks (unchanged) ----------------

#define PSTR 72

__global__ __launch_bounds__(256, 3) void attn_kernel(
    const unsigned short* __restrict__ qkv,
    unsigned short* __restrict__ ctx)
{
  __shared__ __align__(16) unsigned short Ks[2][64*64];
  __shared__ __align__(16) unsigned short Vts[2][64*64];
  __shared__ __align__(16) unsigned short Ps[4][32*PSTR];

  int wg = blockIdx.x + (blockIdx.y << 2) + (blockIdx.z << 6);
  wg = (wg & 7) * 256 + (wg >> 3);
  const int b  = wg >> 6;
  const int h  = (wg >> 2) & 15;
  const int qt = wg & 3;

  const size_t HO  = (((size_t)b)*16 + h)*512*64;
  const size_t PSZ = (size_t)32*16*512*64;
  const unsigned short* Qg  = qkv + HO;
  const unsigned short* Kg  = qkv + PSZ + HO;
  const unsigned short* Vtg = qkv + 2*PSZ + HO;   // [d][l], row stride 512

  const int t    = threadIdx.x;
  const int lane = t & 63;
  const int wave = t >> 6;
  const int quad = lane >> 4;
  const int ln   = lane & 15;

  const int u0 = t, u1 = t + 256;
  const int kr0 = u0 >> 3, kc0 = (u0 & 7) ^ (kr0 & 7);
  const int kr1 = u1 >> 3, kc1 = (u1 & 7) ^ (kr1 & 7);

  bf16x8 aq[2][2];
  #pragma unroll
  for (int rg = 0; rg < 2; ++rg){
    const int row = qt*128 + rg*64 + wave*16 + ln;
    #pragma unroll
    for (int ks = 0; ks < 2; ++ks)
      aq[rg][ks] = *(const bf16x8*)(Qg + (size_t)row*64 + ks*32 + quad*8);
  }

  const int ktEnd = 2*qt + 1;

  __builtin_amdgcn_global_load_lds((gas_t)(Kg  + kr0*64  + kc0*8), (las_t)(Ks[0]  + u0*8), 16,0,0);
  __builtin_amdgcn_global_load_lds((gas_t)(Kg  + kr1*64  + kc1*8), (las_t)(Ks[0]  + u1*8), 16,0,0);
  __builtin_amdgcn_global_load_lds((gas_t)(Vtg + kr0*512 + kc0*8), (las_t)(Vts[0] + u0*8), 16,0,0);
  __builtin_amdgcn_global_load_lds((gas_t)(Vtg + kr1*512 + kc1*8), (las_t)(Vts[0] + u1*8), 16,0,0);

  float m_r[2][4], l_r[2][4];
  #pragma unroll
  for (int rg = 0; rg < 2; ++rg)
    #pragma unroll
    for (int r = 0; r < 4; ++r){ m_r[rg][r] = -3e38f; l_r[rg][r] = 0.f; }
  f32x4 o[2][4] = {};

  const int swzl = ln & 7;
  unsigned short* Pw = Ps[wave];
  const int rowoff = wave*16 + quad*4;

  for (int kt = 0; kt <= ktEnd; ++kt){
    __syncthreads();
    if (kt < ktEnd){
      const unsigned short* Kn  = Kg + (kt+1)*4096;
      const int col = (kt+1)*64;
      unsigned short* kb = Ks[(kt+1)&1];
      unsigned short* vb = Vts[(kt+1)&1];
      __builtin_amdgcn_global_load_lds((gas_t)(Kn  + kr0*64 + kc0*8),        (las_t)(kb + u0*8), 16,0,0);
      __builtin_amdgcn_global_load_lds((gas_t)(Kn  + kr1*64 + kc1*8),        (las_t)(kb + u1*8), 16,0,0);
      __builtin_amdgcn_global_load_lds((gas_t)(Vtg + kr0*512 + col + kc0*8), (las_t)(vb + u0*8), 16,0,0);
      __builtin_amdgcn_global_load_lds((gas_t)(Vtg + kr1*512 + col + kc1*8), (las_t)(vb + u1*8), 16,0,0);
    }
    const unsigned short* ks_ = Ks[kt&1];
    const unsigned short* vt_ = Vts[kt&1];

    #pragma unroll
    for (int rg = 0; rg < 2; ++rg){
      if (rg == 0 && kt > 2*qt) continue;
      const bool diag = (kt == 2*qt + rg);

      f32x4 s[4] = {};
      __builtin_amdgcn_s_setprio(1);
      #pragma unroll
      for (int ks2 = 0; ks2 < 2; ++ks2){
        #pragma unroll
        for (int kn = 0; kn < 4; ++kn){
          const bf16x8 bk = *(const bf16x8*)(ks_ + (kn*16+ln)*64 + (((quad + ks2*4) ^ swzl))*8);
          s[kn] = __builtin_amdgcn_mfma_f32_16x16x32_bf16(aq[rg][ks2], bk, s[kn], 0, 0, 0);
        }
      }
      __builtin_amdgcn_s_setprio(0);

      float p[4][4], lm[4] = {-3e38f,-3e38f,-3e38f,-3e38f};
      #pragma unroll
      for (int kn = 0; kn < 4; ++kn){
        const int col = kn*16 + ln;
        #pragma unroll
        for (int r = 0; r < 4; ++r){
          float v = s[kn][r] * 0.125f;
          if (diag && col > rowoff + r) v = -1e9f;
          p[kn][r] = v;
          lm[r] = fmaxf(lm[r], v);
        }
      }
      #pragma unroll
      for (int off = 1; off < 16; off <<= 1)
        #pragma unroll
        for (int r = 0; r < 4; ++r)
          lm[r] = fmaxf(lm[r], __shfl_xor(lm[r], off, 64));
      float alpha[4], rsum[4];
      #pragma unroll
      for (int r = 0; r < 4; ++r){
        const float mn = fmaxf(m_r[rg][r], lm[r]);
        alpha[r] = __expf(m_r[rg][r] - mn);
        m_r[rg][r] = mn;
      }
      #pragma unroll
      for (int kn = 0; kn < 4; ++kn)
        #pragma unroll
        for (int r = 0; r < 4; ++r)
          p[kn][r] = __expf(p[kn][r] - m_r[rg][r]);
      #pragma unroll
      for (int r = 0; r < 4; ++r)
        rsum[r] = (p[0][r] + p[1][r]) + (p[2][r] + p[3][r]);
      #pragma unroll
      for (int off = 1; off < 16; off <<= 1)
        #pragma unroll
        for (int r = 0; r < 4; ++r)
          rsum[r] += __shfl_xor(rsum[r], off, 64);
      #pragma unroll
      for (int r = 0; r < 4; ++r) l_r[rg][r] = l_r[rg][r]*alpha[r] + rsum[r];
      #pragma unroll
      for (int dn = 0; dn < 4; ++dn)
        #pragma unroll
        for (int r = 0; r < 4; ++r)
          o[rg][dn][r] *= alpha[r];

      #pragma unroll
      for (int kn = 0; kn < 4; ++kn)
        #pragma unroll
        for (int r = 0; r < 4; ++r)
          Pw[(rg*16 + quad*4 + r)*PSTR + kn*16 + ln] = f2bf(p[kn][r]);

      __builtin_amdgcn_s_setprio(1);
      #pragma unroll
      for (int ks2 = 0; ks2 < 2; ++ks2){
        const bf16x8 ap = *(const bf16x8*)(Pw + (rg*16 + ln)*PSTR + quad*8 + ks2*32);
        #pragma unroll
        for (int dn = 0; dn < 4; ++dn){
          const bf16x8 bv = *(const bf16x8*)(vt_ + (dn*16+ln)*64 + (((quad + ks2*4) ^ swzl))*8);
          o[rg][dn] = __builtin_amdgcn_mfma_f32_16x16x32_bf16(ap, bv, o[rg][dn], 0, 0, 0);
        }
      }
      __builtin_amdgcn_s_setprio(0);
    }
  }

  #pragma unroll
  for (int rg = 0; rg < 2; ++rg){
    #pragma unroll
    for (int r = 0; r < 4; ++r){
      const float inv = 1.0f / l_r[rg][r];
      const int row = qt*128 + rg*64 + wave*16 + quad*4 + r;
      unsigned short* op = ctx + ((size_t)b*512 + row)*1024 + h*64 + ln;
      #pragma unroll
      for (int dn = 0; dn < 4; ++dn)
        op[dn*16] = f2bf(o[rg][dn][r] * inv);
    }
  }
}

// ---------------- launch ----------------

extern "C" void kernel_launch(void* const* d_in, const int* in_sizes, int n_in,
                              void* d_out, int out_size, void* d_ws, size_t ws_size,
                              hipStream_t stream) {
  const float* x     = (const float*)d_in[0];
  const float* qw    = (const float*)d_in[1];
  const float* kw    = (const float*)d_in[2];
  const float* vw    = (const float*)d_in[3];
  const float* ow    = (const float*)d_in[4];
  const float* rw    = (const float*)d_in[5];
  const float* rbias = (const float*)d_in[6];
  float* out = (float*)d_out;
  char* ws = (char*)d_ws;

  float* part            = (float*)(ws + OFF_PART);
  int* routes            = (int*)(ws + OFF_ROUTES);
  unsigned short* xb     = (unsigned short*)(ws + OFF_XB);
  unsigned short* wt     = (unsigned short*)(ws + OFF_WT);
  unsigned short* qkvbuf = (unsigned short*)(ws + OFF_QKV);
  unsigned short* ctx    = xb;
  float* probs = out + (size_t)32*512*1024;

  meanpool_kernel<<<dim3(32, 16), 256, 0, stream>>>(x, part, xb);
  router_kernel<<<32, 256, 0, stream>>>(part, rw, rbias, probs, routes);
  wcast_kernel<<<dim3(16, 16, 8), 256, 0, stream>>>(qw, wt);
  wcast_kernel<<<dim3(16, 16, 8), 256, 0, stream>>>(kw, wt + (size_t)8*1024*1024);
  wcast_kernel<<<dim3(16, 16, 8), 256, 0, stream>>>(vw, wt + (size_t)16*1024*1024);
  wcast_kernel<<<dim3(16, 16, 8), 256, 0, stream>>>(ow, wt + (size_t)24*1024*1024);
  gemm_kernel<0><<<dim3(8, 96), 512, 0, stream>>>(xb, wt, routes, qkvbuf, nullptr);
  attn_kernel<<<dim3(4, 16, 32), 256, 0, stream>>>(qkvbuf, ctx);
  gemm_kernel<1><<<dim3(8, 32), 512, 0, stream>>>(ctx, wt + (size_t)24*1024*1024, routes,
                                                  nullptr, out);
}

// Round 6
// 509.836 us; speedup vs baseline: 1.0275x; 1.0001x over previous
//
#include <hip/hip_runtime.h>

// RoutedSelfAttention on MI355X.
// meanpool+cast (vectorized) -> router (ILP reduce + wave shuffle) -> wcast (single fused
// launch, float4/ushort4 64x64 LDS transpose) -> MFMA GEMM qkv as 3 per-projection
// dispatches (256x256 tile, BK=64, 8 waves, 4-phase pipelined schedule, XCD-swizzled;
// e = wn + ln*4 + fn column mapping -> ushort4 full-line stores + lane-local RoPE)
// -> bf16 MFMA flash attention (plain block order) -> MFMA GEMM out.

typedef __attribute__((ext_vector_type(8))) short bf16x8;
typedef __attribute__((ext_vector_type(4))) float f32x4;

typedef const __attribute__((address_space(1))) unsigned short* gas_t;
typedef __attribute__((address_space(3))) unsigned short* las_t;

#define OFF_PART   (0ull)            // [32][16][1024] f32 partial mean sums (2 MB)
#define OFF_ROUTES (2ull << 20)      // [32] int
#define OFF_XB     (3ull << 20)      // x bf16 [32][512][1024] (32 MB); reused as ctx
#define OFF_WT     (40ull << 20)     // W^T bf16 [4][8][1024][1024] (64 MB)
#define OFF_QKV    (112ull << 20)    // q,k [p][32][16][512][64]; vT [32][16][64][512] (96 MB)

__device__ __forceinline__ unsigned short f2bf(float f){
  unsigned int u = __float_as_uint(f);
  u += 0x7fffu + ((u >> 16) & 1u);          // RNE
  return (unsigned short)(u >> 16);
}

// ---------------- meanpool fused with bf16 cast (float4 / ushort4) ----------------

__global__ void meanpool_kernel(const float* __restrict__ x, float* __restrict__ part,
                                unsigned short* __restrict__ xb){
  const int b = blockIdx.x, lc = blockIdx.y, t = threadIdx.x;
  const size_t base = ((size_t)b*512 + lc*32)*1024;
  const float* xs = x + base;
  unsigned short* xo = xb + base;
  float4 a = {0.f, 0.f, 0.f, 0.f};
  for (int l = 0; l < 32; ++l){
    const float4 v = *(const float4*)(xs + l*1024 + t*4);
    a.x += v.x; a.y += v.y; a.z += v.z; a.w += v.w;
    ushort4 pk;
    pk.x = f2bf(v.x); pk.y = f2bf(v.y); pk.z = f2bf(v.z); pk.w = f2bf(v.w);
    *(ushort4*)(xo + l*1024 + t*4) = pk;
  }
  *(float4*)(part + ((size_t)b*16 + lc)*1024 + t*4) = a;
}

// ---------------- router: ILP row-reduce + wave shuffle reduction ----------------

__global__ void router_kernel(const float* __restrict__ part,
                              const float* __restrict__ rw,
                              const float* __restrict__ rbias,
                              float* __restrict__ probs,
                              int* __restrict__ routes){
  const int b = blockIdx.x, t = threadIdx.x;
  const int lane = t & 63, wave = t >> 6;
  __shared__ float wred[4][8];
  float p[8] = {0.f,0.f,0.f,0.f,0.f,0.f,0.f,0.f};
  #pragma unroll
  for (int k = 0; k < 4; ++k){
    const int d = t + k*256;
    float s = 0.f;
    #pragma unroll
    for (int lc = 0; lc < 16; ++lc)             // 16 independent loads (ILP)
      s += part[((size_t)b*16 + lc)*1024 + d];
    s *= (1.0f/512.0f);
    const float4 w0 = *(const float4*)(rw + d*8);
    const float4 w1 = *(const float4*)(rw + d*8 + 4);
    p[0] = fmaf(s, w0.x, p[0]); p[1] = fmaf(s, w0.y, p[1]);
    p[2] = fmaf(s, w0.z, p[2]); p[3] = fmaf(s, w0.w, p[3]);
    p[4] = fmaf(s, w1.x, p[4]); p[5] = fmaf(s, w1.y, p[5]);
    p[6] = fmaf(s, w1.z, p[6]); p[7] = fmaf(s, w1.w, p[7]);
  }
  #pragma unroll
  for (int off = 1; off < 64; off <<= 1)
    #pragma unroll
    for (int e = 0; e < 8; ++e)
      p[e] += __shfl_xor(p[e], off, 64);
  if (lane == 0){
    #pragma unroll
    for (int e = 0; e < 8; ++e) wred[wave][e] = p[e];
  }
  __syncthreads();
  if (t == 0){
    float lg[8], mx = -3e38f; int am = 0;
    #pragma unroll
    for (int e = 0; e < 8; ++e){
      lg[e] = wred[0][e] + wred[1][e] + wred[2][e] + wred[3][e] + rbias[e];
      if (lg[e] > mx){ mx = lg[e]; am = e; }
    }
    float sum = 0.f, ex[8];
    #pragma unroll
    for (int e = 0; e < 8; ++e){ ex[e] = __expf(lg[e] - mx); sum += ex[e]; }
    const float inv = 1.0f / sum;
    #pragma unroll
    for (int e = 0; e < 8; ++e) probs[b*8 + e] = ex[e] * inv;
    routes[b] = am;
  }
}

// ------------- weight transpose-cast: single launch, z = proj*8 + expert -------------

__global__ void wcast_kernel(const float* __restrict__ qw, const float* __restrict__ kw,
                             const float* __restrict__ vw, const float* __restrict__ ow,
                             unsigned short* __restrict__ Wt){
  __shared__ float tile[64][65];
  const int z = blockIdx.z;
  const float* Wm = (z < 8 ? qw : z < 16 ? kw : z < 24 ? vw : ow) + (size_t)(z & 7)*1024*1024;
  unsigned short* Wo = Wt + (size_t)z*1024*1024;
  const int t = threadIdx.x;
  const int r = t >> 4;          // 0..15
  const int c4 = t & 15;         // 0..15 (x4 cols)
  const int gx = blockIdx.x*64, gy = blockIdx.y*64;
  #pragma unroll
  for (int k = 0; k < 4; ++k){
    const int rr = r + 16*k;
    const float4 v = *(const float4*)(Wm + (size_t)(gy + rr)*1024 + gx + c4*4);
    tile[rr][c4*4+0] = v.x; tile[rr][c4*4+1] = v.y;
    tile[rr][c4*4+2] = v.z; tile[rr][c4*4+3] = v.w;
  }
  __syncthreads();
  #pragma unroll
  for (int k = 0; k < 4; ++k){
    const int rr = r + 16*k;
    ushort4 pk;
    pk.x = f2bf(tile[c4*4+0][rr]); pk.y = f2bf(tile[c4*4+1][rr]);
    pk.z = f2bf(tile[c4*4+2][rr]); pk.w = f2bf(tile[c4*4+3][rr]);
    *(ushort4*)(Wo + (size_t)(gx + rr)*1024 + gy + c4*4) = pk;
  }
}

// ---------------- bf16 MFMA GEMM, 256x256 tile, BK=64, 8 waves, phase pipeline --------
// One dispatch per projection (pp runtime arg): grid (8,32) = 256 wgs = exactly one CU
// round. Output-column mapping: e = n0 + wn + ln*4 + fn -> ushort4/float4 dense stores;
// lane-local RoPE. B-frag LDS rows wn+ln*4+fn; B swizzle slot = chunk ^ ((row>>2)&7).
// MODE 0: A=xb[b], W=Wt[pp*8+route]; pp<2: RoPE -> q/k [pp][b][h][l][d]; pp==2: vT
// MODE 1: A=ctx[b], W=Wt_o[route]; -> d_out fp32

template<int MODE>
__global__ __launch_bounds__(512, 2) void gemm_kernel(
    const unsigned short* __restrict__ A,
    const unsigned short* __restrict__ Wt,
    const int* __restrict__ routes,
    unsigned short* __restrict__ qkvout,
    float* __restrict__ outf,
    int pp)
{
  __shared__ __align__(16) unsigned short As[2][256*64];
  __shared__ __align__(16) unsigned short Bs[2][256*64];

  // XCD-contiguous swizzle over 256 wgs (CH = 32 per XCD).
  const int f = blockIdx.x + blockIdx.y*8;
  const int wg = (f & 7)*32 + (f >> 3);
  const int b    = wg >> 3;
  const int tile = wg & 7;
  const int m0 = (tile >> 2)*256;
  const int n0 = (tile & 3)*256;

  const int route = routes[b];
  const unsigned short* Ab = A + (size_t)b*512*1024;
  const unsigned short* Wb = Wt + (size_t)((MODE == 0) ? (pp*8 + route) : route)*1024*1024;

  const int t = threadIdx.x;
  const int lane = t & 63;
  const int wave = t >> 6;          // 0..7
  const int wm = (wave >> 2)*128;   // 2 waves in M
  const int wn = (wave & 3)*64;     // 4 waves in N
  const int quad = lane >> 4;
  const int ln = lane & 15;

  // staging: unit u=t (+k_*512); row = k_*64 + (t>>3); A slot xor = row&7 -> (t>>3)&7;
  // B slot xor = (row>>2)&7 -> (t>>5)&7 (both k_-invariant since 64,16 are mult of 8).
  const int srow = t >> 3;
  const int schA = (t & 7) ^ (srow & 7);
  const int schB = (t & 7) ^ ((t >> 5) & 7);
  const unsigned short* gA0 = Ab + (size_t)(m0 + srow)*1024 + schA*8;
  const unsigned short* gB0 = Wb + (size_t)(n0 + srow)*1024 + schB*8;

  // reader offsets (elems): A rows wm+f*16+ln (xor ln&7); B rows wn+ln*4+fn (xor ln&7).
  const int w8 = ln & 7;
  const int aO0 = (wm + ln)*64 + ((quad    ) ^ w8)*8;
  const int aO1 = (wm + ln)*64 + ((quad + 4) ^ w8)*8;
  const int bO0 = (wn + ln*4)*64 + ((quad    ) ^ w8)*8;
  const int bO1 = (wn + ln*4)*64 + ((quad + 4) ^ w8)*8;

  f32x4 acc[8][4] = {};
  bf16x8 a0[4][2], a1[4][2], b01[2][2], b23[2][2];

#define STAGE(c_, T_) do { \
    const size_t ko_ = (size_t)(T_)*64; \
    las_t dA_ = (las_t)(&As[c_][0]) + (size_t)t*8; \
    las_t dB_ = (las_t)(&Bs[c_][0]) + (size_t)t*8; \
    _Pragma("unroll") \
    for (int k_ = 0; k_ < 4; ++k_){ \
      __builtin_amdgcn_global_load_lds((gas_t)(gA0 + ko_ + (size_t)k_*65536), dA_ + k_*4096, 16, 0, 0); \
      __builtin_amdgcn_global_load_lds((gas_t)(gB0 + ko_ + (size_t)k_*65536), dB_ + k_*4096, 16, 0, 0); \
    } \
  } while (0)

#define RD(ptr_, off_) (*(const bf16x8*)((ptr_) + (off_)))
#define READ_F0(pA_, pB_) do { \
    _Pragma("unroll") for (int f_ = 0; f_ < 4; ++f_){ \
      a0[f_][0] = RD(pA_, aO0 + f_*1024); a0[f_][1] = RD(pA_, aO1 + f_*1024); } \
    _Pragma("unroll") for (int f_ = 0; f_ < 2; ++f_){ \
      b01[f_][0] = RD(pB_, bO0 + f_*64); b01[f_][1] = RD(pB_, bO1 + f_*64); } \
  } while (0)
#define READ_F1(pA_) do { \
    _Pragma("unroll") for (int f_ = 0; f_ < 4; ++f_){ \
      a1[f_][0] = RD(pA_, aO0 + (4+f_)*1024); a1[f_][1] = RD(pA_, aO1 + (4+f_)*1024); } \
  } while (0)
#define READ_F2(pB_) do { \
    _Pragma("unroll") for (int f_ = 0; f_ < 2; ++f_){ \
      b23[f_][0] = RD(pB_, bO0 + (2+f_)*64); b23[f_][1] = RD(pB_, bO1 + (2+f_)*64); } \
  } while (0)

#define MSET(AF_, BF_, IB_, JB_) do { \
    _Pragma("unroll") for (int f_ = 0; f_ < 4; ++f_) \
    _Pragma("unroll") for (int n_ = 0; n_ < 2; ++n_) \
    _Pragma("unroll") for (int k_ = 0; k_ < 2; ++k_) \
      acc[IB_+f_][JB_+n_] = __builtin_amdgcn_mfma_f32_16x16x32_bf16( \
          AF_[f_][k_], BF_[n_][k_], acc[IB_+f_][JB_+n_], 0, 0, 0); \
  } while (0)

  STAGE(0, 0);
  STAGE(1, 1);
  asm volatile("s_waitcnt vmcnt(8)" ::: "memory");
  __builtin_amdgcn_s_barrier();
  READ_F0((&As[0][0]), (&Bs[0][0]));

  for (int g = 0; g < 16; ++g){
    const int c = g & 1;
    const unsigned short* pA  = &As[c][0];
    const unsigned short* pB  = &Bs[c][0];
    const unsigned short* pAn = &As[c ^ 1][0];
    const unsigned short* pBn = &Bs[c ^ 1][0];

    READ_F1(pA);
    __builtin_amdgcn_s_barrier();
    asm volatile("s_waitcnt lgkmcnt(8)" ::: "memory");
    __builtin_amdgcn_sched_barrier(0);
    __builtin_amdgcn_s_setprio(1);
    MSET(a0, b01, 0, 0);
    __builtin_amdgcn_s_setprio(0);
    __builtin_amdgcn_s_barrier();

    READ_F2(pB);
    __builtin_amdgcn_s_barrier();
    asm volatile("s_waitcnt lgkmcnt(4)" ::: "memory");
    __builtin_amdgcn_sched_barrier(0);
    __builtin_amdgcn_s_setprio(1);
    MSET(a1, b01, 4, 0);
    __builtin_amdgcn_s_setprio(0);
    __builtin_amdgcn_s_barrier();

    asm volatile("s_waitcnt lgkmcnt(0)" ::: "memory");
    __builtin_amdgcn_sched_barrier(0);
    __builtin_amdgcn_s_setprio(1);
    MSET(a1, b23, 4, 2);
    __builtin_amdgcn_s_setprio(0);
    __builtin_amdgcn_s_barrier();

    if (g < 14){
      STAGE(c, g + 2);
      asm volatile("s_waitcnt vmcnt(8)" ::: "memory");
    } else if (g == 14){
      asm volatile("s_waitcnt vmcnt(0)" ::: "memory");
    }
    __builtin_amdgcn_s_barrier();
    __builtin_amdgcn_s_setprio(1);
    MSET(a0, b23, 0, 2);
    __builtin_amdgcn_s_setprio(0);
    if (g < 15) READ_F0(pAn, pBn);
    __builtin_amdgcn_s_barrier();
  }
#undef STAGE
#undef RD
#undef READ_F0
#undef READ_F1
#undef READ_F2
#undef MSET

  if (MODE == 0){
    const size_t PSZ = (size_t)32*16*512*64;
    const int h = (n0 + wn) >> 6;       // wave's 64-e block = exactly one head
    if (pp < 2){
      // lane-local RoPE: lane owns e = {4ln..4ln+3}; pairs at freqs i0=2ln, i1=2ln+1.
      // Angle-addition rotation across the 4 consecutive positions r.
      const int eh0 = ln*4;
      const float invf0 = exp2f(-0.41524101f * (float)(ln*2)); // 10000^(-2i/64)
      const float invf1 = invf0 * 0.74989420832f;              // * 10000^(-1/32)
      float sc0, cc0, sc1, cc1;
      __sincosf(invf0, &sc0, &cc0);
      __sincosf(invf1, &sc1, &cc1);
      unsigned short* outp = qkvout + ((((size_t)pp*32 + b)*16 + h)*512)*64 + eh0;
      #pragma unroll
      for (int fm = 0; fm < 8; ++fm){
        const int l0 = m0 + wm + fm*16 + quad*4;
        float s0, c0, s1, c1;
        __sincosf((float)l0 * invf0, &s0, &c0);
        __sincosf((float)l0 * invf1, &s1, &c1);
        #pragma unroll
        for (int r = 0; r < 4; ++r){
          const int l = l0 + r;
          const float x0 = acc[fm][0][r], x1 = acc[fm][1][r];
          const float x2 = acc[fm][2][r], x3 = acc[fm][3][r];
          ushort4 pk;
          pk.x = f2bf(x0*c0 - x1*s0);
          pk.y = f2bf(x1*c0 + x0*s0);
          pk.z = f2bf(x2*c1 - x3*s1);
          pk.w = f2bf(x3*c1 + x2*s1);
          *(ushort4*)(outp + (size_t)l*64) = pk;
          const float nc0 = c0*cc0 - s0*sc0, ns0 = s0*cc0 + c0*sc0;
          const float nc1 = c1*cc1 - s1*sc1, ns1 = s1*cc1 + c1*sc1;
          c0 = nc0; s0 = ns0; c1 = nc1; s1 = ns1;
        }
      }
    } else {
      // vT[b][h][d][l]: pack 4 consecutive l (r=0..3) into one 8B store
      #pragma unroll
      for (int fn = 0; fn < 4; ++fn){
        const int eh = ln*4 + fn;
        unsigned short* outp = qkvout + 2*PSZ + (((size_t)b*16 + h)*64 + eh)*512;
        #pragma unroll
        for (int fm = 0; fm < 8; ++fm){
          const int l0 = m0 + wm + fm*16 + quad*4;
          ushort4 pk;
          pk.x = f2bf(acc[fm][fn][0]); pk.y = f2bf(acc[fm][fn][1]);
          pk.z = f2bf(acc[fm][fn][2]); pk.w = f2bf(acc[fm][fn][3]);
          *(ushort4*)(outp + l0) = pk;
        }
      }
    }
  } else {
    const int e0 = n0 + wn + ln*4;
    #pragma unroll
    for (int fm = 0; fm < 8; ++fm){
      #pragma unroll
      for (int r = 0; r < 4; ++r){
        const int l = m0 + wm + fm*16 + quad*4 + r;
        float4 f4;
        f4.x = acc[fm][0][r]; f4.y = acc[fm][1][r];
        f4.z = acc[fm][2][r]; f4.w = acc[fm][3][r];
        *(float4*)(outf + ((size_t)b*512 + l)*1024 + e0) = f4;
      }
    }
  }
}

// ---------------- bf16 MFMA flash attention, 128-row Q blocks ----------------
// Plain block order (qt fastest): co-scheduled blocks mix qt (work = 2qt+2) for load
// balance, and same-(b,h) blocks stay adjacent for K/V L2 sharing.

#define PSTR 72

__global__ __launch_bounds__(256, 3) void attn_kernel(
    const unsigned short* __restrict__ qkv,
    unsigned short* __restrict__ ctx)
{
  __shared__ __align__(16) unsigned short Ks[2][64*64];
  __shared__ __align__(16) unsigned short Vts[2][64*64];
  __shared__ __align__(16) unsigned short Ps[4][32*PSTR];

  const int qt = blockIdx.x, h = blockIdx.y, b = blockIdx.z;

  const size_t HO  = (((size_t)b)*16 + h)*512*64;
  const size_t PSZ = (size_t)32*16*512*64;
  const unsigned short* Qg  = qkv + HO;
  const unsigned short* Kg  = qkv + PSZ + HO;
  const unsigned short* Vtg = qkv + 2*PSZ + HO;   // [d][l], row stride 512

  const int t    = threadIdx.x;
  const int lane = t & 63;
  const int wave = t >> 6;
  const int quad = lane >> 4;
  const int ln   = lane & 15;

  const int u0 = t, u1 = t + 256;
  const int kr0 = u0 >> 3, kc0 = (u0 & 7) ^ (kr0 & 7);
  const int kr1 = u1 >> 3, kc1 = (u1 & 7) ^ (kr1 & 7);

  bf16x8 aq[2][2];
  #pragma unroll
  for (int rg = 0; rg < 2; ++rg){
    const int row = qt*128 + rg*64 + wave*16 + ln;
    #pragma unroll
    for (int ks = 0; ks < 2; ++ks)
      aq[rg][ks] = *(const bf16x8*)(Qg + (size_t)row*64 + ks*32 + quad*8);
  }

  const int ktEnd = 2*qt + 1;

  __builtin_amdgcn_global_load_lds((gas_t)(Kg  + kr0*64  + kc0*8), (las_t)(Ks[0]  + u0*8), 16,0,0);
  __builtin_amdgcn_global_load_lds((gas_t)(Kg  + kr1*64  + kc1*8), (las_t)(Ks[0]  + u1*8), 16,0,0);
  __builtin_amdgcn_global_load_lds((gas_t)(Vtg + kr0*512 + kc0*8), (las_t)(Vts[0] + u0*8), 16,0,0);
  __builtin_amdgcn_global_load_lds((gas_t)(Vtg + kr1*512 + kc1*8), (las_t)(Vts[0] + u1*8), 16,0,0);

  float m_r[2][4], l_r[2][4];
  #pragma unroll
  for (int rg = 0; rg < 2; ++rg)
    #pragma unroll
    for (int r = 0; r < 4; ++r){ m_r[rg][r] = -3e38f; l_r[rg][r] = 0.f; }
  f32x4 o[2][4] = {};

  const int swzl = ln & 7;
  unsigned short* Pw = Ps[wave];
  const int rowoff = wave*16 + quad*4;

  for (int kt = 0; kt <= ktEnd; ++kt){
    __syncthreads();
    if (kt < ktEnd){
      const unsigned short* Kn  = Kg + (kt+1)*4096;
      const int col = (kt+1)*64;
      unsigned short* kb = Ks[(kt+1)&1];
      unsigned short* vb = Vts[(kt+1)&1];
      __builtin_amdgcn_global_load_lds((gas_t)(Kn  + kr0*64 + kc0*8),        (las_t)(kb + u0*8), 16,0,0);
      __builtin_amdgcn_global_load_lds((gas_t)(Kn  + kr1*64 + kc1*8),        (las_t)(kb + u1*8), 16,0,0);
      __builtin_amdgcn_global_load_lds((gas_t)(Vtg + kr0*512 + col + kc0*8), (las_t)(vb + u0*8), 16,0,0);
      __builtin_amdgcn_global_load_lds((gas_t)(Vtg + kr1*512 + col + kc1*8), (las_t)(vb + u1*8), 16,0,0);
    }
    const unsigned short* ks_ = Ks[kt&1];
    const unsigned short* vt_ = Vts[kt&1];

    #pragma unroll
    for (int rg = 0; rg < 2; ++rg){
      if (rg == 0 && kt > 2*qt) continue;
      const bool diag = (kt == 2*qt + rg);

      f32x4 s[4] = {};
      __builtin_amdgcn_s_setprio(1);
      #pragma unroll
      for (int ks2 = 0; ks2 < 2; ++ks2){
        #pragma unroll
        for (int kn = 0; kn < 4; ++kn){
          const bf16x8 bk = *(const bf16x8*)(ks_ + (kn*16+ln)*64 + (((quad + ks2*4) ^ swzl))*8);
          s[kn] = __builtin_amdgcn_mfma_f32_16x16x32_bf16(aq[rg][ks2], bk, s[kn], 0, 0, 0);
        }
      }
      __builtin_amdgcn_s_setprio(0);

      float p[4][4], lm[4] = {-3e38f,-3e38f,-3e38f,-3e38f};
      #pragma unroll
      for (int kn = 0; kn < 4; ++kn){
        const int col = kn*16 + ln;
        #pragma unroll
        for (int r = 0; r < 4; ++r){
          float v = s[kn][r] * 0.125f;
          if (diag && col > rowoff + r) v = -1e9f;
          p[kn][r] = v;
          lm[r] = fmaxf(lm[r], v);
        }
      }
      #pragma unroll
      for (int off = 1; off < 16; off <<= 1)
        #pragma unroll
        for (int r = 0; r < 4; ++r)
          lm[r] = fmaxf(lm[r], __shfl_xor(lm[r], off, 64));
      float alpha[4], rsum[4];
      #pragma unroll
      for (int r = 0; r < 4; ++r){
        const float mn = fmaxf(m_r[rg][r], lm[r]);
        alpha[r] = __expf(m_r[rg][r] - mn);
        m_r[rg][r] = mn;
      }
      #pragma unroll
      for (int kn = 0; kn < 4; ++kn)
        #pragma unroll
        for (int r = 0; r < 4; ++r)
          p[kn][r] = __expf(p[kn][r] - m_r[rg][r]);
      #pragma unroll
      for (int r = 0; r < 4; ++r)
        rsum[r] = (p[0][r] + p[1][r]) + (p[2][r] + p[3][r]);
      #pragma unroll
      for (int off = 1; off < 16; off <<= 1)
        #pragma unroll
        for (int r = 0; r < 4; ++r)
          rsum[r] += __shfl_xor(rsum[r], off, 64);
      #pragma unroll
      for (int r = 0; r < 4; ++r) l_r[rg][r] = l_r[rg][r]*alpha[r] + rsum[r];
      #pragma unroll
      for (int dn = 0; dn < 4; ++dn)
        #pragma unroll
        for (int r = 0; r < 4; ++r)
          o[rg][dn][r] *= alpha[r];

      #pragma unroll
      for (int kn = 0; kn < 4; ++kn)
        #pragma unroll
        for (int r = 0; r < 4; ++r)
          Pw[(rg*16 + quad*4 + r)*PSTR + kn*16 + ln] = f2bf(p[kn][r]);

      __builtin_amdgcn_s_setprio(1);
      #pragma unroll
      for (int ks2 = 0; ks2 < 2; ++ks2){
        const bf16x8 ap = *(const bf16x8*)(Pw + (rg*16 + ln)*PSTR + quad*8 + ks2*32);
        #pragma unroll
        for (int dn = 0; dn < 4; ++dn){
          const bf16x8 bv = *(const bf16x8*)(vt_ + (dn*16+ln)*64 + (((quad + ks2*4) ^ swzl))*8);
          o[rg][dn] = __builtin_amdgcn_mfma_f32_16x16x32_bf16(ap, bv, o[rg][dn], 0, 0, 0);
        }
      }
      __builtin_amdgcn_s_setprio(0);
    }
  }

  #pragma unroll
  for (int rg = 0; rg < 2; ++rg){
    #pragma unroll
    for (int r = 0; r < 4; ++r){
      const float inv = 1.0f / l_r[rg][r];
      const int row = qt*128 + rg*64 + wave*16 + quad*4 + r;
      unsigned short* op = ctx + ((size_t)b*512 + row)*1024 + h*64 + ln;
      #pragma unroll
      for (int dn = 0; dn < 4; ++dn)
        op[dn*16] = f2bf(o[rg][dn][r] * inv);
    }
  }
}

// ---------------- launch ----------------

extern "C" void kernel_launch(void* const* d_in, const int* in_sizes, int n_in,
                              void* d_out, int out_size, void* d_ws, size_t ws_size,
                              hipStream_t stream) {
  const float* x     = (const float*)d_in[0];
  const float* qw    = (const float*)d_in[1];
  const float* kw    = (const float*)d_in[2];
  const float* vw    = (const float*)d_in[3];
  const float* ow    = (const float*)d_in[4];
  const float* rw    = (const float*)d_in[5];
  const float* rbias = (const float*)d_in[6];
  float* out = (float*)d_out;
  char* ws = (char*)d_ws;

  float* part            = (float*)(ws + OFF_PART);
  int* routes            = (int*)(ws + OFF_ROUTES);
  unsigned short* xb     = (unsigned short*)(ws + OFF_XB);
  unsigned short* wt     = (unsigned short*)(ws + OFF_WT);
  unsigned short* qkvbuf = (unsigned short*)(ws + OFF_QKV);
  unsigned short* ctx    = xb;
  float* probs = out + (size_t)32*512*1024;

  meanpool_kernel<<<dim3(32, 16), 256, 0, stream>>>(x, part, xb);
  router_kernel<<<32, 256, 0, stream>>>(part, rw, rbias, probs, routes);
  wcast_kernel<<<dim3(16, 16, 32), 256, 0, stream>>>(qw, kw, vw, ow, wt);
  gemm_kernel<0><<<dim3(8, 32), 512, 0, stream>>>(xb, wt, routes, qkvbuf, nullptr, 0);
  gemm_kernel<0><<<dim3(8, 32), 512, 0, stream>>>(xb, wt, routes, qkvbuf, nullptr, 1);
  gemm_kernel<0><<<dim3(8, 32), 512, 0, stream>>>(xb, wt, routes, qkvbuf, nullptr, 2);
  attn_kernel<<<dim3(4, 16, 32), 256, 0, stream>>>(qkvbuf, ctx);
  gemm_kernel<1><<<dim3(8, 32), 512, 0, stream>>>(ctx, wt + (size_t)24*1024*1024, routes,
                                                  nullptr, out, 0);
}